// Round 2
// baseline (875.249 us; speedup 1.0000x reference)
//
#include <hip/hip_runtime.h>
#include <math.h>

#define N_NODES 100000
#define N_EDGES 1600000

static __device__ __forceinline__ float bf2f(unsigned int u16) {
    return __uint_as_float(u16 << 16);
}
static __device__ __forceinline__ unsigned short f2bf(float f) {
    unsigned u = __float_as_uint(f);
    unsigned r = u + 0x7FFF + ((u >> 16) & 1);   // RTNE
    return (unsigned short)(r >> 16);
}

// ---------------- weight repack: W1[128][256] = [Wrel0|Wrel1|Wrel2|Wroot],
// W2[64][512] = [Wq|Wk|Wv|Wskip], bcat[512] ----------------
__global__ void repack_kernel(const float* __restrict__ Wrel, const float* __restrict__ Wroot,
                              const float* __restrict__ Wq, const float* __restrict__ Wk,
                              const float* __restrict__ Wv, const float* __restrict__ Wsk,
                              const float* __restrict__ bq, const float* __restrict__ bk,
                              const float* __restrict__ bv, const float* __restrict__ bsk,
                              float* __restrict__ W1, float* __restrict__ W2, float* __restrict__ bcat) {
    int idx = blockIdx.x * 256 + threadIdx.x;
    if (idx < 128 * 256) {
        int k = idx >> 8, c = idx & 255;
        float v;
        if (c < 192) { int r = c >> 6, cc = c & 63; v = Wrel[r * 8192 + k * 64 + cc]; }
        else v = Wroot[k * 64 + (c - 192)];
        W1[idx] = v;
    }
    int i2 = idx - 128 * 256;
    if (i2 >= 0 && i2 < 64 * 512) {
        int k = i2 >> 9, c = i2 & 511;
        float v;
        if (c < 128) v = Wq[k * 128 + c];
        else if (c < 256) v = Wk[k * 128 + c - 128];
        else if (c < 384) v = Wv[k * 128 + c - 256];
        else v = Wsk[k * 128 + c - 384];
        W2[i2] = v;
    }
    int i3 = idx - 128 * 256 - 64 * 512;
    if (i3 >= 0 && i3 < 512) {
        float v;
        if (i3 < 128) v = bq[i3];
        else if (i3 < 256) v = bk[i3 - 128];
        else if (i3 < 384) v = bv[i3 - 256];
        else v = bsk[i3 - 384];
        bcat[i3] = v;
    }
}

// ---------------- CSR build ----------------
__global__ void hist_kernel(const int* __restrict__ ei, int* __restrict__ deg) {
    int e = blockIdx.x * 256 + threadIdx.x;
    if (e < N_EDGES) atomicAdd(&deg[ei[N_EDGES + e]], 1);
}

__global__ void scanA_kernel(const int* __restrict__ deg, int* __restrict__ part) {
    __shared__ int wsum[4];
    int t = threadIdx.x;
    int base = blockIdx.x * 1024 + t * 4;
    int s = 0;
    for (int i = 0; i < 4; i++) { int idx = base + i; if (idx < N_NODES) s += deg[idx]; }
    for (int off = 1; off < 64; off <<= 1) s += __shfl_xor(s, off);
    if ((t & 63) == 0) wsum[t >> 6] = s;
    __syncthreads();
    if (t == 0) part[blockIdx.x] = wsum[0] + wsum[1] + wsum[2] + wsum[3];
}

__global__ void scanB_kernel(int* __restrict__ part, int* __restrict__ rs, int nb) {
    int run = 0;
    for (int b = 0; b < nb; b++) { int v = part[b]; part[b] = run; run += v; }
    rs[N_NODES] = run;
}

__global__ void scanC_kernel(const int* __restrict__ deg, const int* __restrict__ part,
                             int* __restrict__ rs) {
    __shared__ int wsum[4];
    int t = threadIdx.x;
    int base = blockIdx.x * 1024 + t * 4;
    int v[4]; int tsum = 0;
    for (int i = 0; i < 4; i++) { int idx = base + i; v[i] = (idx < N_NODES) ? deg[idx] : 0; tsum += v[i]; }
    int x = tsum;
    int lane = t & 63;
    for (int off = 1; off < 64; off <<= 1) { int y = __shfl_up(x, off); if (lane >= off) x += y; }
    if (lane == 63) wsum[t >> 6] = x;
    __syncthreads();
    if (t == 0) { int run = 0; for (int w = 0; w < 4; w++) { int tmp = wsum[w]; wsum[w] = run; run += tmp; } }
    __syncthreads();
    int excl = x - tsum + wsum[t >> 6] + part[blockIdx.x];
    for (int i = 0; i < 4; i++) {
        int idx = base + i;
        if (idx < N_NODES) rs[idx] = excl;
        excl += v[i];
    }
}

__global__ void scatter_kernel(const int* __restrict__ ei, const int* __restrict__ et,
                               const int* __restrict__ rs, int* __restrict__ fill,
                               unsigned int* __restrict__ ep) {
    int e = blockIdx.x * 256 + threadIdx.x;
    if (e >= N_EDGES) return;
    int src = ei[e], dst = ei[N_EDGES + e], r = et[e];
    int pos = rs[dst] + atomicAdd(&fill[dst], 1);
    ep[pos] = (unsigned)src | ((unsigned)r << 20);   // src < 2^20, r < 4
}

// ---------------- GEMM1: X[N,128] @ W1[128,256] -> hr_all(bf16 [N,192]), hroot(f32 [N,64]) ----------------
__global__ __launch_bounds__(256) void gemm1_kernel(const float* __restrict__ X, const float* __restrict__ W1,
                                                    unsigned short* __restrict__ hr_all, float* __restrict__ hroot) {
    __shared__ float As[64][68];
    __shared__ float Bs[64][64];
    int t = threadIdx.x;
    int rb = blockIdx.x * 64, cb = blockIdx.y * 64;
    int tc = t & 15, tm = t >> 4;
    float acc[4][4] = {};
    for (int kk = 0; kk < 128; kk += 64) {
        for (int i = 0; i < 4; i++) {
            int lin = t * 4 + i * 1024;
            int m = lin >> 6, k = lin & 63;
            int row = rb + m;
            float4 a = (row < N_NODES) ? *(const float4*)&X[row * 128 + kk + k] : make_float4(0, 0, 0, 0);
            As[k][m] = a.x; As[k + 1][m] = a.y; As[k + 2][m] = a.z; As[k + 3][m] = a.w;
        }
        for (int i = 0; i < 4; i++) {
            int lin = t * 4 + i * 1024;
            int k = lin >> 6, c = lin & 63;
            *(float4*)&Bs[k][c] = *(const float4*)&W1[(kk + k) * 256 + cb + c];
        }
        __syncthreads();
        #pragma unroll 8
        for (int k = 0; k < 64; k++) {
            float4 a = *(const float4*)&As[k][tm * 4];
            float4 b = *(const float4*)&Bs[k][tc * 4];
            float av[4] = {a.x, a.y, a.z, a.w};
            float bv[4] = {b.x, b.y, b.z, b.w};
            #pragma unroll
            for (int i = 0; i < 4; i++)
                #pragma unroll
                for (int j = 0; j < 4; j++) acc[i][j] += av[i] * bv[j];
        }
        __syncthreads();
    }
    for (int i = 0; i < 4; i++) {
        int row = rb + tm * 4 + i;
        if (row >= N_NODES) break;
        for (int j = 0; j < 4; j++) {
            int c = cb + tc * 4 + j;
            float v = acc[i][j];
            if (c < 192) hr_all[row * 192 + c] = f2bf(v);
            else hroot[row * 64 + (c - 192)] = v;
        }
    }
}

// ---------------- RGCN aggregate: one wave per node, per-relation mean ----------------
__global__ __launch_bounds__(256) void rgcn_kernel(const unsigned short* __restrict__ hr_all,
                                                   const float* __restrict__ hroot,
                                                   const float* __restrict__ brg, const int* __restrict__ rs,
                                                   const unsigned int* __restrict__ ep,
                                                   unsigned short* __restrict__ Hm) {
    int lane = threadIdx.x & 63;
    int n = blockIdx.x * 4 + (threadIdx.x >> 6);
    if (n >= N_NODES) return;
    int p0 = rs[n], p1 = rs[n + 1];
    float a0 = 0.f, a1 = 0.f, a2 = 0.f, c0 = 0.f, c1 = 0.f, c2 = 0.f;
    for (int p = p0; p < p1; p++) {
        unsigned pe = ep[p];
        int src = pe & 0xFFFFF;
        int r = pe >> 20;
        float v = bf2f(hr_all[src * 192 + r * 64 + lane]);
        if (r == 0) { a0 += v; c0 += 1.f; }
        else if (r == 1) { a1 += v; c1 += 1.f; }
        else { a2 += v; c2 += 1.f; }
    }
    float h = hroot[n * 64 + lane] + brg[lane];
    if (c0 > 0.f) h += a0 / c0;
    if (c1 > 0.f) h += a1 / c1;
    if (c2 > 0.f) h += a2 / c2;
    Hm[n * 64 + lane] = f2bf(fmaxf(h, 0.f));
}

// ---------------- GEMM2: Hm(bf16 [N,64]) @ W2[64,512] + bcat -> Qb,Kb,Vb (bf16 [N,128]) + agg(skip, f32) ----------------
__global__ __launch_bounds__(256) void gemm2_kernel(const unsigned short* __restrict__ Hm,
                                                    const float* __restrict__ W2,
                                                    const float* __restrict__ bcat,
                                                    unsigned short* __restrict__ Qb, unsigned short* __restrict__ Kb,
                                                    unsigned short* __restrict__ Vb, float* __restrict__ agg) {
    __shared__ float As[64][68];
    __shared__ float Bs[64][64];
    int t = threadIdx.x;
    int rb = blockIdx.x * 64, cb = blockIdx.y * 64;
    int tc = t & 15, tm = t >> 4;
    for (int i = 0; i < 4; i++) {
        int lin = t * 4 + i * 1024;
        int m = lin >> 6, k = lin & 63;
        int row = rb + m;
        uint2 a = (row < N_NODES) ? *(const uint2*)&Hm[row * 64 + k] : make_uint2(0, 0);
        As[k][m]     = bf2f(a.x & 0xFFFF);
        As[k + 1][m] = bf2f(a.x >> 16);
        As[k + 2][m] = bf2f(a.y & 0xFFFF);
        As[k + 3][m] = bf2f(a.y >> 16);
    }
    for (int i = 0; i < 4; i++) {
        int lin = t * 4 + i * 1024;
        int k = lin >> 6, c = lin & 63;
        *(float4*)&Bs[k][c] = *(const float4*)&W2[k * 512 + cb + c];
    }
    __syncthreads();
    float acc[4][4] = {};
    #pragma unroll 8
    for (int k = 0; k < 64; k++) {
        float4 a = *(const float4*)&As[k][tm * 4];
        float4 b = *(const float4*)&Bs[k][tc * 4];
        float av[4] = {a.x, a.y, a.z, a.w};
        float bv[4] = {b.x, b.y, b.z, b.w};
        #pragma unroll
        for (int i = 0; i < 4; i++)
            #pragma unroll
            for (int j = 0; j < 4; j++) acc[i][j] += av[i] * bv[j];
    }
    for (int i = 0; i < 4; i++) {
        int row = rb + tm * 4 + i;
        if (row >= N_NODES) break;
        for (int j = 0; j < 4; j++) {
            int c = cb + tc * 4 + j;
            float v = acc[i][j] + bcat[c];
            if (c < 128) Qb[row * 128 + c] = f2bf(v);
            else if (c < 256) Kb[row * 128 + (c - 128)] = f2bf(v);
            else if (c < 384) Vb[row * 128 + (c - 256)] = f2bf(v);
            else agg[row * 128 + (c - 384)] = v;
        }
    }
}

// ---------------- fused attention: one wave per dst node, online softmax, agg += attn out ----------------
__global__ __launch_bounds__(256) void attn_kernel(const unsigned short* __restrict__ Qb,
                                                   const unsigned short* __restrict__ Kb,
                                                   const unsigned short* __restrict__ Vb,
                                                   const int* __restrict__ rs, const unsigned int* __restrict__ ep,
                                                   float* __restrict__ agg) {
    int lane = threadIdx.x & 63;
    int n = blockIdx.x * 4 + (threadIdx.x >> 6);
    if (n >= N_NODES) return;
    const unsigned int* Qu = (const unsigned int*)Qb;
    const unsigned int* Ku = (const unsigned int*)Kb;
    const unsigned int* Vu = (const unsigned int*)Vb;
    // lane holds dims (2*lane, 2*lane+1); head = lane/16; 16-lane groups reduce per-head dots
    unsigned qw = Qu[n * 64 + lane];
    float q0 = bf2f(qw & 0xFFFF), q1 = bf2f(qw >> 16);
    float m = -INFINITY, d = 0.f, o0 = 0.f, o1 = 0.f;
    int p0 = rs[n], p1 = rs[n + 1];
    for (int p = p0; p < p1; p++) {
        unsigned pe = ep[p];
        int src = pe & 0xFFFFF;
        unsigned kw = Ku[src * 64 + lane];
        unsigned vw = Vu[src * 64 + lane];
        float partial = q0 * bf2f(kw & 0xFFFF) + q1 * bf2f(kw >> 16);
        partial += __shfl_xor(partial, 1);
        partial += __shfl_xor(partial, 2);
        partial += __shfl_xor(partial, 4);
        partial += __shfl_xor(partial, 8);
        float s = partial * 0.17677669529663687f;  // 1/sqrt(32)
        float mn = fmaxf(m, s);
        float scale = __expf(m - mn);   // m=-inf first iter -> 0
        float pw = __expf(s - mn);
        d = d * scale + pw;
        o0 = o0 * scale + pw * bf2f(vw & 0xFFFF);
        o1 = o1 * scale + pw * bf2f(vw >> 16);
        m = mn;
    }
    if (d > 0.f) {
        int idx = n * 128 + lane * 2;
        agg[idx] += o0 / d;
        agg[idx + 1] += o1 / d;
    }
}

// ---------------- final: out = relu(agg) @ Wf + bf ; 8 lanes per node ----------------
__global__ __launch_bounds__(256) void final_kernel(const float* __restrict__ agg, const float* __restrict__ Wf,
                                                    const float* __restrict__ bfv, float* __restrict__ out) {
    int t = threadIdx.x;
    int node = blockIdx.x * 32 + (t >> 3);
    int sl = t & 7;
    if (node >= N_NODES) return;
    float acc[7] = {};
    const float4* ap = (const float4*)&agg[node * 128 + sl * 16];
    #pragma unroll
    for (int q = 0; q < 4; q++) {
        float4 v4 = ap[q];
        float vv[4] = {v4.x, v4.y, v4.z, v4.w};
        #pragma unroll
        for (int u = 0; u < 4; u++) {
            float v = fmaxf(vv[u], 0.f);
            int k = sl * 16 + q * 4 + u;
            #pragma unroll
            for (int j = 0; j < 7; j++) acc[j] += v * Wf[k * 7 + j];
        }
    }
    #pragma unroll
    for (int j = 0; j < 7; j++) {
        acc[j] += __shfl_xor(acc[j], 1);
        acc[j] += __shfl_xor(acc[j], 2);
        acc[j] += __shfl_xor(acc[j], 4);
    }
    if (sl == 0) {
        #pragma unroll
        for (int j = 0; j < 7; j++) out[node * 7 + j] = acc[j] + bfv[j];
    }
}

extern "C" void kernel_launch(void* const* d_in, const int* in_sizes, int n_in,
                              void* d_out, int out_size, void* d_ws, size_t ws_size,
                              hipStream_t stream) {
    const float* x     = (const float*)d_in[0];
    const int*   ei    = (const int*)d_in[2];
    const int*   et    = (const int*)d_in[3];
    const float* Wrel  = (const float*)d_in[4];
    const float* Wroot = (const float*)d_in[5];
    const float* brg   = (const float*)d_in[6];
    const float* Wq    = (const float*)d_in[7];
    const float* bq    = (const float*)d_in[8];
    const float* Wk    = (const float*)d_in[9];
    const float* bk    = (const float*)d_in[10];
    const float* Wv    = (const float*)d_in[11];
    const float* bv    = (const float*)d_in[12];
    const float* Wsk   = (const float*)d_in[13];
    const float* bsk   = (const float*)d_in[14];
    const float* Wf    = (const float*)d_in[15];
    const float* bfv   = (const float*)d_in[16];
    float* out = (float*)d_out;

    // workspace layout (~148.7 MB total):
    //  [0,        38.4M)  hr_all  bf16 [N,192]   (dead after rgcn)
    //  [38.4M,    64.0M)  hroot   f32  [N,64]    (dead after rgcn)
    //  [0,        76.8M)  Qb|Kb|Vb bf16 [N,128]x3 (overlay, written by gemm2)
    //  [76.8M,    89.6M)  Hm      bf16 [N,64]
    //  [89.6M,   140.8M)  agg     f32  [N,128]
    //  [140.8M,  147.2M)  ep      u32  [E]
    //  then rs/deg/fill/part/W1/W2/bcat
    char* ws = (char*)d_ws;
    unsigned short* hr_all = (unsigned short*)(ws + 0);
    unsigned short* Qb     = (unsigned short*)(ws + 0);
    unsigned short* Kb     = (unsigned short*)(ws + 25600000);
    unsigned short* Vb     = (unsigned short*)(ws + 51200000);
    float*          hroot  = (float*)(ws + 38400000);
    unsigned short* Hm     = (unsigned short*)(ws + 76800000);
    float*          agg    = (float*)(ws + 89600000);
    unsigned int*   ep     = (unsigned int*)(ws + 140800000);
    int*            rs     = (int*)(ws + 147200000);
    int*            deg    = (int*)(ws + 147600016);
    int*            fill   = (int*)(ws + 148000032);
    int*            part   = (int*)(ws + 148400048);
    float*          W1     = (float*)(ws + 148400560);
    float*          W2     = (float*)(ws + 148531632);
    float*          bcat   = (float*)(ws + 148662704);

    hipMemsetAsync(deg, 0, N_NODES * sizeof(int), stream);
    hipMemsetAsync(fill, 0, N_NODES * sizeof(int), stream);

    repack_kernel<<<258, 256, 0, stream>>>(Wrel, Wroot, Wq, Wk, Wv, Wsk, bq, bk, bv, bsk, W1, W2, bcat);

    // CSR build by destination
    hist_kernel<<<N_EDGES / 256, 256, 0, stream>>>(ei, deg);
    scanA_kernel<<<98, 256, 0, stream>>>(deg, part);
    scanB_kernel<<<1, 1, 0, stream>>>(part, rs, 98);
    scanC_kernel<<<98, 256, 0, stream>>>(deg, part, rs);
    scatter_kernel<<<N_EDGES / 256, 256, 0, stream>>>(ei, et, rs, fill, ep);

    // RGCN
    gemm1_kernel<<<dim3(1563, 4), 256, 0, stream>>>(x, W1, hr_all, hroot);
    rgcn_kernel<<<25000, 256, 0, stream>>>(hr_all, hroot, brg, rs, ep, Hm);

    // TransformerConv
    gemm2_kernel<<<dim3(1563, 8), 256, 0, stream>>>(Hm, W2, bcat, Qb, Kb, Vb, agg);
    attn_kernel<<<25000, 256, 0, stream>>>(Qb, Kb, Vb, rs, ep, agg);

    // classifier
    final_kernel<<<3125, 256, 0, stream>>>(agg, Wf, bfv, out);
}

// Round 3
// 575.860 us; speedup vs baseline: 1.5199x; 1.5199x over previous
//
#include <hip/hip_runtime.h>
#include <math.h>

#define N_NODES 100000
#define N_EDGES 1600000

typedef short short8 __attribute__((ext_vector_type(8)));
typedef float f32x4 __attribute__((ext_vector_type(4)));

static __device__ __forceinline__ float bf2f(unsigned int u16) {
    return __uint_as_float(u16 << 16);
}
static __device__ __forceinline__ unsigned short f2bf(float f) {
    unsigned u = __float_as_uint(f);
    unsigned r = u + 0x7FFF + ((u >> 16) & 1);   // RTNE
    return (unsigned short)(r >> 16);
}

// ---------------- weight repack:
// W1t bf16 [256][128]: col-major cat of [Wrel0|Wrel1|Wrel2|Wroot] (c = output col, k = input dim)
// W2t bf16 [512][64]:  col-major cat of [Wq|Wk|Wv|Wskip]
// bcat f32 [512]
__global__ void repack_kernel(const float* __restrict__ Wrel, const float* __restrict__ Wroot,
                              const float* __restrict__ Wq, const float* __restrict__ Wk,
                              const float* __restrict__ Wv, const float* __restrict__ Wsk,
                              const float* __restrict__ bq, const float* __restrict__ bk,
                              const float* __restrict__ bv, const float* __restrict__ bsk,
                              unsigned short* __restrict__ W1t, unsigned short* __restrict__ W2t,
                              float* __restrict__ bcat) {
    int idx = blockIdx.x * 256 + threadIdx.x;
    if (idx < 128 * 256) {
        int k = idx >> 8, c = idx & 255;
        float v;
        if (c < 192) { int r = c >> 6, cc = c & 63; v = Wrel[r * 8192 + k * 64 + cc]; }
        else v = Wroot[k * 64 + (c - 192)];
        W1t[c * 128 + k] = f2bf(v);
    }
    int i2 = idx - 128 * 256;
    if (i2 >= 0 && i2 < 64 * 512) {
        int k = i2 >> 9, c = i2 & 511;
        float v;
        if (c < 128) v = Wq[k * 128 + c];
        else if (c < 256) v = Wk[k * 128 + c - 128];
        else if (c < 384) v = Wv[k * 128 + c - 256];
        else v = Wsk[k * 128 + c - 384];
        W2t[c * 64 + k] = f2bf(v);
    }
    int i3 = idx - 128 * 256 - 64 * 512;
    if (i3 >= 0 && i3 < 512) {
        float v;
        if (i3 < 128) v = bq[i3];
        else if (i3 < 256) v = bk[i3 - 128];
        else if (i3 < 384) v = bv[i3 - 256];
        else v = bsk[i3 - 384];
        bcat[i3] = v;
    }
}

// ---------------- CSR build ----------------
__global__ void hist_kernel(const int* __restrict__ ei, int* __restrict__ deg) {
    int e = blockIdx.x * 256 + threadIdx.x;
    if (e < N_EDGES) atomicAdd(&deg[ei[N_EDGES + e]], 1);
}

__global__ void scanA_kernel(const int* __restrict__ deg, int* __restrict__ part) {
    __shared__ int wsum[4];
    int t = threadIdx.x;
    int base = blockIdx.x * 1024 + t * 4;
    int s = 0;
    for (int i = 0; i < 4; i++) { int idx = base + i; if (idx < N_NODES) s += deg[idx]; }
    for (int off = 1; off < 64; off <<= 1) s += __shfl_xor(s, off);
    if ((t & 63) == 0) wsum[t >> 6] = s;
    __syncthreads();
    if (t == 0) part[blockIdx.x] = wsum[0] + wsum[1] + wsum[2] + wsum[3];
}

__global__ void scanB_kernel(int* __restrict__ part, int* __restrict__ rs, int nb) {
    int run = 0;
    for (int b = 0; b < nb; b++) { int v = part[b]; part[b] = run; run += v; }
    rs[N_NODES] = run;
}

__global__ void scanC_kernel(const int* __restrict__ deg, const int* __restrict__ part,
                             int* __restrict__ rs) {
    __shared__ int wsum[4];
    int t = threadIdx.x;
    int base = blockIdx.x * 1024 + t * 4;
    int v[4]; int tsum = 0;
    for (int i = 0; i < 4; i++) { int idx = base + i; v[i] = (idx < N_NODES) ? deg[idx] : 0; tsum += v[i]; }
    int x = tsum;
    int lane = t & 63;
    for (int off = 1; off < 64; off <<= 1) { int y = __shfl_up(x, off); if (lane >= off) x += y; }
    if (lane == 63) wsum[t >> 6] = x;
    __syncthreads();
    if (t == 0) { int run = 0; for (int w = 0; w < 4; w++) { int tmp = wsum[w]; wsum[w] = run; run += tmp; } }
    __syncthreads();
    int excl = x - tsum + wsum[t >> 6] + part[blockIdx.x];
    for (int i = 0; i < 4; i++) {
        int idx = base + i;
        if (idx < N_NODES) rs[idx] = excl;
        excl += v[i];
    }
}

__global__ void scatter_kernel(const int* __restrict__ ei, const int* __restrict__ et,
                               const int* __restrict__ rs, int* __restrict__ fill,
                               unsigned int* __restrict__ ep) {
    int e = blockIdx.x * 256 + threadIdx.x;
    if (e >= N_EDGES) return;
    int src = ei[e], dst = ei[N_EDGES + e], r = et[e];
    int pos = rs[dst] + atomicAdd(&fill[dst], 1);
    ep[pos] = (unsigned)src | ((unsigned)r << 20);   // src < 2^20, r < 4
}

// ---------------- GEMM1 (MFMA bf16): X[N,128] @ W1[128,256] -> hr_all(bf16 [N,192]), hroot(f32 [N,64]) ----------------
__global__ __launch_bounds__(256) void gemm1_mfma(const float* __restrict__ X,
                                                  const unsigned short* __restrict__ W1t,
                                                  unsigned short* __restrict__ hr_all,
                                                  float* __restrict__ hroot) {
    __shared__ unsigned short As[64][136];   // 64 rows x 128 k, +8 pad (stride 272B = 16*17)
    __shared__ unsigned short Bs[64][136];   // 64 cols x 128 k
    int t = threadIdx.x;
    int rb = blockIdx.x * 64, cb = blockIdx.y * 64;
    // stage A (f32 -> bf16)
    #pragma unroll
    for (int i = 0; i < 8; i++) {
        int lin = t + i * 256;      // 0..2047
        int row = lin >> 5;         // 32 float4 per row
        int c4 = lin & 31;
        float4 v = make_float4(0.f, 0.f, 0.f, 0.f);
        int gr = rb + row;
        if (gr < N_NODES) v = *(const float4*)&X[gr * 128 + c4 * 4];
        unsigned w0 = (unsigned)f2bf(v.x) | ((unsigned)f2bf(v.y) << 16);
        unsigned w1 = (unsigned)f2bf(v.z) | ((unsigned)f2bf(v.w) << 16);
        *(uint2*)&As[row][c4 * 4] = make_uint2(w0, w1);
    }
    // stage B (bf16 copy)
    #pragma unroll
    for (int i = 0; i < 4; i++) {
        int lin = t + i * 256;      // 0..1023
        int n = lin >> 4;
        int k8 = lin & 15;
        *(uint4*)&Bs[n][k8 * 8] = *(const uint4*)&W1t[(cb + n) * 128 + k8 * 8];
    }
    __syncthreads();
    int w = t >> 6, l = t & 63;
    int wr = (w >> 1) * 32, wc = (w & 1) * 32;
    int lr = l & 15, lk = (l >> 4) * 8;
    f32x4 c00 = {0.f,0.f,0.f,0.f}, c01 = {0.f,0.f,0.f,0.f};
    f32x4 c10 = {0.f,0.f,0.f,0.f}, c11 = {0.f,0.f,0.f,0.f};
    #pragma unroll
    for (int kk = 0; kk < 128; kk += 32) {
        short8 a0 = *(const short8*)&As[wr + lr][kk + lk];
        short8 a1 = *(const short8*)&As[wr + 16 + lr][kk + lk];
        short8 b0 = *(const short8*)&Bs[wc + lr][kk + lk];
        short8 b1 = *(const short8*)&Bs[wc + 16 + lr][kk + lk];
        c00 = __builtin_amdgcn_mfma_f32_16x16x32_bf16(a0, b0, c00, 0, 0, 0);
        c01 = __builtin_amdgcn_mfma_f32_16x16x32_bf16(a0, b1, c01, 0, 0, 0);
        c10 = __builtin_amdgcn_mfma_f32_16x16x32_bf16(a1, b0, c10, 0, 0, 0);
        c11 = __builtin_amdgcn_mfma_f32_16x16x32_bf16(a1, b1, c11, 0, 0, 0);
    }
    int drow = (l >> 4) * 2 * 2;   // (lane>>4)*4
    int dcol = l & 15;
    f32x4 cc[2][2] = {{c00, c01}, {c10, c11}};
    #pragma unroll
    for (int i = 0; i < 2; i++)
        #pragma unroll
        for (int j = 0; j < 2; j++)
            #pragma unroll
            for (int rg = 0; rg < 4; rg++) {
                int gr = rb + wr + i * 16 + drow + rg;
                int gc = cb + wc + j * 16 + dcol;
                if (gr >= N_NODES) continue;
                float v = cc[i][j][rg];
                if (gc < 192) hr_all[gr * 192 + gc] = f2bf(v);
                else hroot[gr * 64 + (gc - 192)] = v;
            }
}

// ---------------- RGCN aggregate: one wave per node, chunked edge broadcast ----------------
__global__ __launch_bounds__(256) void rgcn_kernel(const unsigned short* __restrict__ hr_all,
                                                   const float* __restrict__ hroot,
                                                   const float* __restrict__ brg, const int* __restrict__ rs,
                                                   const unsigned int* __restrict__ ep,
                                                   unsigned short* __restrict__ Hm) {
    int lane = threadIdx.x & 63;
    int n = blockIdx.x * 4 + (threadIdx.x >> 6);
    if (n >= N_NODES) return;
    int p0 = rs[n], p1 = rs[n + 1];
    float a0 = 0.f, a1 = 0.f, a2 = 0.f, c0 = 0.f, c1 = 0.f, c2 = 0.f;
    for (int base = p0; base < p1; base += 64) {
        int pc = base + lane;
        int chunk = (pc < p1) ? (int)ep[pc] : 0;
        int cnt = min(64, p1 - base);
        int j = 0;
        for (; j + 1 < cnt; j += 2) {
            int pa = __builtin_amdgcn_readlane(chunk, j);
            int pb = __builtin_amdgcn_readlane(chunk, j + 1);
            int sa = pa & 0xFFFFF, ra = pa >> 20;
            int sb = pb & 0xFFFFF, rb2 = pb >> 20;
            float va = bf2f(hr_all[sa * 192 + ra * 64 + lane]);
            float vb = bf2f(hr_all[sb * 192 + rb2 * 64 + lane]);
            if (ra == 0) { a0 += va; c0 += 1.f; } else if (ra == 1) { a1 += va; c1 += 1.f; } else { a2 += va; c2 += 1.f; }
            if (rb2 == 0) { a0 += vb; c0 += 1.f; } else if (rb2 == 1) { a1 += vb; c1 += 1.f; } else { a2 += vb; c2 += 1.f; }
        }
        if (j < cnt) {
            int pa = __builtin_amdgcn_readlane(chunk, j);
            int sa = pa & 0xFFFFF, ra = pa >> 20;
            float va = bf2f(hr_all[sa * 192 + ra * 64 + lane]);
            if (ra == 0) { a0 += va; c0 += 1.f; } else if (ra == 1) { a1 += va; c1 += 1.f; } else { a2 += va; c2 += 1.f; }
        }
    }
    float h = hroot[n * 64 + lane] + brg[lane];
    if (c0 > 0.f) h += a0 / c0;
    if (c1 > 0.f) h += a1 / c1;
    if (c2 > 0.f) h += a2 / c2;
    Hm[n * 64 + lane] = f2bf(fmaxf(h, 0.f));
}

// ---------------- GEMM2 (MFMA bf16): Hm[N,64] @ W2[64,512] + bcat -> Qb,Kb,Vb bf16 + skip f32 ----------------
__global__ __launch_bounds__(256) void gemm2_mfma(const unsigned short* __restrict__ Hm,
                                                  const unsigned short* __restrict__ W2t,
                                                  const float* __restrict__ bcat,
                                                  unsigned short* __restrict__ Qb, unsigned short* __restrict__ Kb,
                                                  unsigned short* __restrict__ Vb, float* __restrict__ skip) {
    __shared__ unsigned short As[64][72];   // 64 rows x 64 k, +8 pad (stride 144B = 16*9)
    __shared__ unsigned short Bs[64][72];
    int t = threadIdx.x;
    int rb = blockIdx.x * 64, cb = blockIdx.y * 64;
    #pragma unroll
    for (int i = 0; i < 2; i++) {
        int lin = t + i * 256;      // 0..511
        int row = lin >> 3;
        int k8 = lin & 7;
        uint4 v = make_uint4(0, 0, 0, 0);
        int gr = rb + row;
        if (gr < N_NODES) v = *(const uint4*)&Hm[gr * 64 + k8 * 8];
        *(uint4*)&As[row][k8 * 8] = v;
    }
    #pragma unroll
    for (int i = 0; i < 2; i++) {
        int lin = t + i * 256;
        int n = lin >> 3;
        int k8 = lin & 7;
        *(uint4*)&Bs[n][k8 * 8] = *(const uint4*)&W2t[(cb + n) * 64 + k8 * 8];
    }
    __syncthreads();
    int w = t >> 6, l = t & 63;
    int wr = (w >> 1) * 32, wc = (w & 1) * 32;
    int lr = l & 15, lk = (l >> 4) * 8;
    f32x4 c00 = {0.f,0.f,0.f,0.f}, c01 = {0.f,0.f,0.f,0.f};
    f32x4 c10 = {0.f,0.f,0.f,0.f}, c11 = {0.f,0.f,0.f,0.f};
    #pragma unroll
    for (int kk = 0; kk < 64; kk += 32) {
        short8 a0 = *(const short8*)&As[wr + lr][kk + lk];
        short8 a1 = *(const short8*)&As[wr + 16 + lr][kk + lk];
        short8 b0 = *(const short8*)&Bs[wc + lr][kk + lk];
        short8 b1 = *(const short8*)&Bs[wc + 16 + lr][kk + lk];
        c00 = __builtin_amdgcn_mfma_f32_16x16x32_bf16(a0, b0, c00, 0, 0, 0);
        c01 = __builtin_amdgcn_mfma_f32_16x16x32_bf16(a0, b1, c01, 0, 0, 0);
        c10 = __builtin_amdgcn_mfma_f32_16x16x32_bf16(a1, b0, c10, 0, 0, 0);
        c11 = __builtin_amdgcn_mfma_f32_16x16x32_bf16(a1, b1, c11, 0, 0, 0);
    }
    int drow = (l >> 4) * 4;
    int dcol = l & 15;
    f32x4 cc[2][2] = {{c00, c01}, {c10, c11}};
    #pragma unroll
    for (int i = 0; i < 2; i++)
        #pragma unroll
        for (int j = 0; j < 2; j++)
            #pragma unroll
            for (int rg = 0; rg < 4; rg++) {
                int gr = rb + wr + i * 16 + drow + rg;
                int gc = cb + wc + j * 16 + dcol;
                if (gr >= N_NODES) continue;
                float v = cc[i][j][rg] + bcat[gc];
                if (gc < 128) Qb[gr * 128 + gc] = f2bf(v);
                else if (gc < 256) Kb[gr * 128 + (gc - 128)] = f2bf(v);
                else if (gc < 384) Vb[gr * 128 + (gc - 256)] = f2bf(v);
                else skip[gr * 128 + (gc - 384)] = v;
            }
}

// ---------------- fused attention + classifier: one wave per dst node ----------------
// softmax computed without max-subtraction (shift-invariant; scores are O(0.1) here)
__global__ __launch_bounds__(256) void attn_kernel(const unsigned short* __restrict__ Qb,
                                                   const unsigned short* __restrict__ Kb,
                                                   const unsigned short* __restrict__ Vb,
                                                   const int* __restrict__ rs, const unsigned int* __restrict__ ep,
                                                   const float* __restrict__ skip,
                                                   const float* __restrict__ Wf, const float* __restrict__ bfv,
                                                   float* __restrict__ out) {
    int lane = threadIdx.x & 63;
    int n = blockIdx.x * 4 + (threadIdx.x >> 6);
    if (n >= N_NODES) return;
    const unsigned* Qu = (const unsigned*)Qb;
    const unsigned* Ku = (const unsigned*)Kb;
    const unsigned* Vu = (const unsigned*)Vb;
    unsigned qw = Qu[n * 64 + lane];
    const float qs = 0.17677669529663687f;  // 1/sqrt(32)
    float q0 = bf2f(qw & 0xFFFF) * qs, q1 = bf2f(qw >> 16) * qs;
    float wf0[7], wf1[7];
    #pragma unroll
    for (int j = 0; j < 7; j++) { wf0[j] = Wf[(2 * lane) * 7 + j]; wf1[j] = Wf[(2 * lane + 1) * 7 + j]; }
    float d = 0.f, o0 = 0.f, o1 = 0.f;
    int p0 = rs[n], p1 = rs[n + 1];
    for (int base = p0; base < p1; base += 64) {
        int pc = base + lane;
        int chunk = (pc < p1) ? (int)ep[pc] : 0;
        int cnt = min(64, p1 - base);
        int j = 0;
        for (; j + 1 < cnt; j += 2) {
            int pa = __builtin_amdgcn_readlane(chunk, j);
            int pb = __builtin_amdgcn_readlane(chunk, j + 1);
            int sa = pa & 0xFFFFF, sb = pb & 0xFFFFF;
            unsigned ka = Ku[sa * 64 + lane], kb = Ku[sb * 64 + lane];
            unsigned va = Vu[sa * 64 + lane], vb = Vu[sb * 64 + lane];
            float da = q0 * bf2f(ka & 0xFFFF) + q1 * bf2f(ka >> 16);
            float db = q0 * bf2f(kb & 0xFFFF) + q1 * bf2f(kb >> 16);
            da += __shfl_xor(da, 1); db += __shfl_xor(db, 1);
            da += __shfl_xor(da, 2); db += __shfl_xor(db, 2);
            da += __shfl_xor(da, 4); db += __shfl_xor(db, 4);
            da += __shfl_xor(da, 8); db += __shfl_xor(db, 8);
            float pwa = __expf(da), pwb = __expf(db);
            d += pwa + pwb;
            o0 += pwa * bf2f(va & 0xFFFF) + pwb * bf2f(vb & 0xFFFF);
            o1 += pwa * bf2f(va >> 16) + pwb * bf2f(vb >> 16);
        }
        if (j < cnt) {
            int pa = __builtin_amdgcn_readlane(chunk, j);
            int sa = pa & 0xFFFFF;
            unsigned ka = Ku[sa * 64 + lane];
            unsigned va = Vu[sa * 64 + lane];
            float da = q0 * bf2f(ka & 0xFFFF) + q1 * bf2f(ka >> 16);
            da += __shfl_xor(da, 1);
            da += __shfl_xor(da, 2);
            da += __shfl_xor(da, 4);
            da += __shfl_xor(da, 8);
            float pwa = __expf(da);
            d += pwa;
            o0 += pwa * bf2f(va & 0xFFFF);
            o1 += pwa * bf2f(va >> 16);
        }
    }
    float inv = (d > 0.f) ? 1.f / d : 0.f;
    float2 sk = *(const float2*)&skip[n * 128 + lane * 2];
    float r0 = fmaxf(sk.x + o0 * inv, 0.f);
    float r1 = fmaxf(sk.y + o1 * inv, 0.f);
    float acc[7];
    #pragma unroll
    for (int j = 0; j < 7; j++) acc[j] = r0 * wf0[j] + r1 * wf1[j];
    #pragma unroll
    for (int j = 0; j < 7; j++) {
        acc[j] += __shfl_xor(acc[j], 1);
        acc[j] += __shfl_xor(acc[j], 2);
        acc[j] += __shfl_xor(acc[j], 4);
        acc[j] += __shfl_xor(acc[j], 8);
        acc[j] += __shfl_xor(acc[j], 16);
        acc[j] += __shfl_xor(acc[j], 32);
    }
    if (lane == 0) {
        #pragma unroll
        for (int j = 0; j < 7; j++) out[n * 7 + j] = acc[j] + bfv[j];
    }
}

extern "C" void kernel_launch(void* const* d_in, const int* in_sizes, int n_in,
                              void* d_out, int out_size, void* d_ws, size_t ws_size,
                              hipStream_t stream) {
    const float* x     = (const float*)d_in[0];
    const int*   ei    = (const int*)d_in[2];
    const int*   et    = (const int*)d_in[3];
    const float* Wrel  = (const float*)d_in[4];
    const float* Wroot = (const float*)d_in[5];
    const float* brg   = (const float*)d_in[6];
    const float* Wq    = (const float*)d_in[7];
    const float* bq    = (const float*)d_in[8];
    const float* Wk    = (const float*)d_in[9];
    const float* bk    = (const float*)d_in[10];
    const float* Wv    = (const float*)d_in[11];
    const float* bv    = (const float*)d_in[12];
    const float* Wsk   = (const float*)d_in[13];
    const float* bsk   = (const float*)d_in[14];
    const float* Wf    = (const float*)d_in[15];
    const float* bfv   = (const float*)d_in[16];
    float* out = (float*)d_out;

    // workspace layout (~148.6 MB):
    //  [0,      38.4M)  hr_all  bf16 [N,192]  (dead after rgcn)
    //  [38.4M,  64.0M)  hroot   f32  [N,64]   (dead after rgcn)
    //  [0,      76.8M)  Qb|Kb|Vb bf16 [N,128]x3 (overlay, written by gemm2 after rgcn)
    //  [76.8M,  89.6M)  Hm      bf16 [N,64]
    //  [89.6M, 140.8M)  skip    f32  [N,128]
    //  [140.8M,147.2M)  ep      u32  [E]
    //  then rs / deg+fill (contiguous for single memset) / part / W1t / W2t / bcat
    char* ws = (char*)d_ws;
    unsigned short* hr_all = (unsigned short*)(ws + 0);
    unsigned short* Qb     = (unsigned short*)(ws + 0);
    unsigned short* Kb     = (unsigned short*)(ws + 25600000);
    unsigned short* Vb     = (unsigned short*)(ws + 51200000);
    float*          hroot  = (float*)(ws + 38400000);
    unsigned short* Hm     = (unsigned short*)(ws + 76800000);
    float*          skip   = (float*)(ws + 89600000);
    unsigned int*   ep     = (unsigned int*)(ws + 140800000);
    int*            rs     = (int*)(ws + 147200000);
    int*            deg    = (int*)(ws + 147600016);
    int*            fill   = (int*)(ws + 148000016);
    int*            part   = (int*)(ws + 148400016);
    unsigned short* W1t    = (unsigned short*)(ws + 148400528);
    unsigned short* W2t    = (unsigned short*)(ws + 148466064);
    float*          bcat   = (float*)(ws + 148531600);

    hipMemsetAsync(deg, 0, 2 * N_NODES * sizeof(int), stream);   // deg + fill contiguous

    repack_kernel<<<258, 256, 0, stream>>>(Wrel, Wroot, Wq, Wk, Wv, Wsk, bq, bk, bv, bsk, W1t, W2t, bcat);

    // CSR build by destination
    hist_kernel<<<N_EDGES / 256, 256, 0, stream>>>(ei, deg);
    scanA_kernel<<<98, 256, 0, stream>>>(deg, part);
    scanB_kernel<<<1, 1, 0, stream>>>(part, rs, 98);
    scanC_kernel<<<98, 256, 0, stream>>>(deg, part, rs);
    scatter_kernel<<<N_EDGES / 256, 256, 0, stream>>>(ei, et, rs, fill, ep);

    // RGCN
    gemm1_mfma<<<dim3(1563, 4), 256, 0, stream>>>(x, W1t, hr_all, hroot);
    rgcn_kernel<<<25000, 256, 0, stream>>>(hr_all, hroot, brg, rs, ep, Hm);

    // TransformerConv
    gemm2_mfma<<<dim3(1563, 8), 256, 0, stream>>>(Hm, W2t, bcat, Qb, Kb, Vb, skip);
    attn_kernel<<<25000, 256, 0, stream>>>(Qb, Kb, Vb, rs, ep, skip, Wf, bfv, out);
}

// Round 4
// 548.196 us; speedup vs baseline: 1.5966x; 1.0505x over previous
//
#include <hip/hip_runtime.h>
#include <math.h>

#define N_NODES 100000
#define N_EDGES 1600000

typedef short short8 __attribute__((ext_vector_type(8)));
typedef float f32x4 __attribute__((ext_vector_type(4)));

static __device__ __forceinline__ float bf2f(unsigned int u16) {
    return __uint_as_float(u16 << 16);
}
static __device__ __forceinline__ unsigned short f2bf(float f) {
    unsigned u = __float_as_uint(f);
    unsigned r = u + 0x7FFF + ((u >> 16) & 1);   // RTNE
    return (unsigned short)(r >> 16);
}

// ---------------- weight repack:
// W1t bf16 [256][128]: col-major cat of [Wrel0|Wrel1|Wrel2|Wroot]
// W2t bf16 [512][64]:  col-major cat of [Wq|Wk|Wv|Wskip]
// bcat f32 [512]
__global__ void repack_kernel(const float* __restrict__ Wrel, const float* __restrict__ Wroot,
                              const float* __restrict__ Wq, const float* __restrict__ Wk,
                              const float* __restrict__ Wv, const float* __restrict__ Wsk,
                              const float* __restrict__ bq, const float* __restrict__ bk,
                              const float* __restrict__ bv, const float* __restrict__ bsk,
                              unsigned short* __restrict__ W1t, unsigned short* __restrict__ W2t,
                              float* __restrict__ bcat) {
    int idx = blockIdx.x * 256 + threadIdx.x;
    if (idx < 128 * 256) {
        int k = idx >> 8, c = idx & 255;
        float v;
        if (c < 192) { int r = c >> 6, cc = c & 63; v = Wrel[r * 8192 + k * 64 + cc]; }
        else v = Wroot[k * 64 + (c - 192)];
        W1t[c * 128 + k] = f2bf(v);
    }
    int i2 = idx - 128 * 256;
    if (i2 >= 0 && i2 < 64 * 512) {
        int k = i2 >> 9, c = i2 & 511;
        float v;
        if (c < 128) v = Wq[k * 128 + c];
        else if (c < 256) v = Wk[k * 128 + c - 128];
        else if (c < 384) v = Wv[k * 128 + c - 256];
        else v = Wsk[k * 128 + c - 384];
        W2t[c * 64 + k] = f2bf(v);
    }
    int i3 = idx - 128 * 256 - 64 * 512;
    if (i3 >= 0 && i3 < 512) {
        float v;
        if (i3 < 128) v = bq[i3];
        else if (i3 < 256) v = bk[i3 - 128];
        else if (i3 < 384) v = bv[i3 - 256];
        else v = bsk[i3 - 384];
        bcat[i3] = v;
    }
}

// ---------------- CSR build ----------------
__global__ void hist_kernel(const int* __restrict__ ei, int* __restrict__ deg) {
    int e = blockIdx.x * 256 + threadIdx.x;
    if (e < N_EDGES) atomicAdd(&deg[ei[N_EDGES + e]], 1);
}

__global__ void scanA_kernel(const int* __restrict__ deg, int* __restrict__ part) {
    __shared__ int wsum[4];
    int t = threadIdx.x;
    int base = blockIdx.x * 1024 + t * 4;
    int s = 0;
    for (int i = 0; i < 4; i++) { int idx = base + i; if (idx < N_NODES) s += deg[idx]; }
    for (int off = 1; off < 64; off <<= 1) s += __shfl_xor(s, off);
    if ((t & 63) == 0) wsum[t >> 6] = s;
    __syncthreads();
    if (t == 0) part[blockIdx.x] = wsum[0] + wsum[1] + wsum[2] + wsum[3];
}

__global__ void scanB_kernel(int* __restrict__ part, int* __restrict__ rs, int nb) {
    int run = 0;
    for (int b = 0; b < nb; b++) { int v = part[b]; part[b] = run; run += v; }
    rs[N_NODES] = run;
}

__global__ void scanC_kernel(const int* __restrict__ deg, const int* __restrict__ part,
                             int* __restrict__ rs) {
    __shared__ int wsum[4];
    int t = threadIdx.x;
    int base = blockIdx.x * 1024 + t * 4;
    int v[4]; int tsum = 0;
    for (int i = 0; i < 4; i++) { int idx = base + i; v[i] = (idx < N_NODES) ? deg[idx] : 0; tsum += v[i]; }
    int x = tsum;
    int lane = t & 63;
    for (int off = 1; off < 64; off <<= 1) { int y = __shfl_up(x, off); if (lane >= off) x += y; }
    if (lane == 63) wsum[t >> 6] = x;
    __syncthreads();
    if (t == 0) { int run = 0; for (int w = 0; w < 4; w++) { int tmp = wsum[w]; wsum[w] = run; run += tmp; } }
    __syncthreads();
    int excl = x - tsum + wsum[t >> 6] + part[blockIdx.x];
    for (int i = 0; i < 4; i++) {
        int idx = base + i;
        if (idx < N_NODES) rs[idx] = excl;
        excl += v[i];
    }
}

__global__ void scatter_kernel(const int* __restrict__ ei, const int* __restrict__ et,
                               const int* __restrict__ rs, int* __restrict__ fill,
                               unsigned int* __restrict__ ep) {
    int e = blockIdx.x * 256 + threadIdx.x;
    if (e >= N_EDGES) return;
    int src = ei[e], dst = ei[N_EDGES + e], r = et[e];
    int pos = rs[dst] + atomicAdd(&fill[dst], 1);
    ep[pos] = (unsigned)src | ((unsigned)r << 20);   // src < 2^20, r < 4
}

// ---------------- GEMM1 (MFMA bf16): X[N,128] @ W1[128,256] -> hr_all bf16 [N][256]
// (cols 0..191 = per-relation transforms, 192..255 = root) ----------------
__global__ __launch_bounds__(256) void gemm1_mfma(const float* __restrict__ X,
                                                  const unsigned short* __restrict__ W1t,
                                                  unsigned short* __restrict__ hr_all) {
    __shared__ unsigned short As[64][136];   // +8 pad
    __shared__ unsigned short Bs[64][136];
    int t = threadIdx.x;
    int rb = blockIdx.x * 64;
    // stage A once (f32 -> bf16)
    #pragma unroll
    for (int i = 0; i < 8; i++) {
        int lin = t + i * 256;
        int row = lin >> 5;
        int c4 = lin & 31;
        float4 v = make_float4(0.f, 0.f, 0.f, 0.f);
        int gr = rb + row;
        if (gr < N_NODES) v = *(const float4*)&X[gr * 128 + c4 * 4];
        unsigned w0 = (unsigned)f2bf(v.x) | ((unsigned)f2bf(v.y) << 16);
        unsigned w1 = (unsigned)f2bf(v.z) | ((unsigned)f2bf(v.w) << 16);
        *(uint2*)&As[row][c4 * 4] = make_uint2(w0, w1);
    }
    int w = t >> 6, l = t & 63;
    int wr = (w >> 1) * 32, wc = (w & 1) * 32;
    int lr = l & 15, lk = (l >> 4) * 8;
    int drow = (l >> 4) * 4;
    int dcol = l & 15;
    for (int cb4 = 0; cb4 < 4; cb4++) {
        int cb = cb4 * 64;
        __syncthreads();   // waves done with previous Bs (also covers A staging, iter 0)
        #pragma unroll
        for (int i = 0; i < 4; i++) {
            int lin = t + i * 256;
            int n = lin >> 4;
            int k8 = lin & 15;
            *(uint4*)&Bs[n][k8 * 8] = *(const uint4*)&W1t[(cb + n) * 128 + k8 * 8];
        }
        __syncthreads();
        f32x4 c00 = {0.f,0.f,0.f,0.f}, c01 = {0.f,0.f,0.f,0.f};
        f32x4 c10 = {0.f,0.f,0.f,0.f}, c11 = {0.f,0.f,0.f,0.f};
        #pragma unroll
        for (int kk = 0; kk < 128; kk += 32) {
            short8 a0 = *(const short8*)&As[wr + lr][kk + lk];
            short8 a1 = *(const short8*)&As[wr + 16 + lr][kk + lk];
            short8 b0 = *(const short8*)&Bs[wc + lr][kk + lk];
            short8 b1 = *(const short8*)&Bs[wc + 16 + lr][kk + lk];
            c00 = __builtin_amdgcn_mfma_f32_16x16x32_bf16(a0, b0, c00, 0, 0, 0);
            c01 = __builtin_amdgcn_mfma_f32_16x16x32_bf16(a0, b1, c01, 0, 0, 0);
            c10 = __builtin_amdgcn_mfma_f32_16x16x32_bf16(a1, b0, c10, 0, 0, 0);
            c11 = __builtin_amdgcn_mfma_f32_16x16x32_bf16(a1, b1, c11, 0, 0, 0);
        }
        f32x4 cc[2][2] = {{c00, c01}, {c10, c11}};
        #pragma unroll
        for (int i = 0; i < 2; i++)
            #pragma unroll
            for (int j = 0; j < 2; j++)
                #pragma unroll
                for (int rg = 0; rg < 4; rg++) {
                    int gr = rb + wr + i * 16 + drow + rg;
                    int gc = cb + wc + j * 16 + dcol;
                    if (gr < N_NODES) hr_all[gr * 256 + gc] = f2bf(cc[i][j][rg]);
                }
    }
}

// ---------------- RGCN aggregate: one wave per node, chunked broadcast, unroll 4 ----------------
__global__ __launch_bounds__(256) void rgcn_kernel(const unsigned short* __restrict__ hr,
                                                   const float* __restrict__ brg, const int* __restrict__ rs,
                                                   const unsigned int* __restrict__ ep,
                                                   unsigned short* __restrict__ Hm) {
    int lane = threadIdx.x & 63;
    int n = blockIdx.x * 4 + (threadIdx.x >> 6);
    if (n >= N_NODES) return;
    int p0 = rs[n], p1 = rs[n + 1];
    float a0 = 0.f, a1 = 0.f, a2 = 0.f, c0 = 0.f, c1 = 0.f, c2 = 0.f;
    for (int base = p0; base < p1; base += 64) {
        int pc = base + lane;
        int chunk = (pc < p1) ? (int)ep[pc] : 0;
        int cnt = min(64, p1 - base);
        int j = 0;
        for (; j + 3 < cnt; j += 4) {
            int e0 = __builtin_amdgcn_readlane(chunk, j);
            int e1 = __builtin_amdgcn_readlane(chunk, j + 1);
            int e2 = __builtin_amdgcn_readlane(chunk, j + 2);
            int e3 = __builtin_amdgcn_readlane(chunk, j + 3);
            int s0 = e0 & 0xFFFFF, r0 = e0 >> 20;
            int s1 = e1 & 0xFFFFF, r1 = e1 >> 20;
            int s2 = e2 & 0xFFFFF, r2 = e2 >> 20;
            int s3 = e3 & 0xFFFFF, r3 = e3 >> 20;
            float v0 = bf2f(hr[s0 * 256 + r0 * 64 + lane]);
            float v1 = bf2f(hr[s1 * 256 + r1 * 64 + lane]);
            float v2 = bf2f(hr[s2 * 256 + r2 * 64 + lane]);
            float v3 = bf2f(hr[s3 * 256 + r3 * 64 + lane]);
            if (r0 == 0) { a0 += v0; c0 += 1.f; } else if (r0 == 1) { a1 += v0; c1 += 1.f; } else { a2 += v0; c2 += 1.f; }
            if (r1 == 0) { a0 += v1; c0 += 1.f; } else if (r1 == 1) { a1 += v1; c1 += 1.f; } else { a2 += v1; c2 += 1.f; }
            if (r2 == 0) { a0 += v2; c0 += 1.f; } else if (r2 == 1) { a1 += v2; c1 += 1.f; } else { a2 += v2; c2 += 1.f; }
            if (r3 == 0) { a0 += v3; c0 += 1.f; } else if (r3 == 1) { a1 += v3; c1 += 1.f; } else { a2 += v3; c2 += 1.f; }
        }
        for (; j < cnt; j++) {
            int e0 = __builtin_amdgcn_readlane(chunk, j);
            int s0 = e0 & 0xFFFFF, r0 = e0 >> 20;
            float v0 = bf2f(hr[s0 * 256 + r0 * 64 + lane]);
            if (r0 == 0) { a0 += v0; c0 += 1.f; } else if (r0 == 1) { a1 += v0; c1 += 1.f; } else { a2 += v0; c2 += 1.f; }
        }
    }
    float h = bf2f(hr[n * 256 + 192 + lane]) + brg[lane];
    if (c0 > 0.f) h += a0 / c0;
    if (c1 > 0.f) h += a1 / c1;
    if (c2 > 0.f) h += a2 / c2;
    Hm[n * 64 + lane] = f2bf(fmaxf(h, 0.f));
}

// ---------------- GEMM2 (MFMA bf16): Hm[N,64] @ W2[64,512] + bcat -> Qb,Kb,Vb,Sb (all bf16 [N,128]) ----------------
__global__ __launch_bounds__(256) void gemm2_mfma(const unsigned short* __restrict__ Hm,
                                                  const unsigned short* __restrict__ W2t,
                                                  const float* __restrict__ bcat,
                                                  unsigned short* __restrict__ Qb, unsigned short* __restrict__ Kb,
                                                  unsigned short* __restrict__ Vb, unsigned short* __restrict__ Sb) {
    __shared__ unsigned short As[64][72];   // +8 pad
    __shared__ unsigned short Bs[64][72];
    int t = threadIdx.x;
    int rb = blockIdx.x * 64;
    #pragma unroll
    for (int i = 0; i < 2; i++) {
        int lin = t + i * 256;
        int row = lin >> 3;
        int k8 = lin & 7;
        uint4 v = make_uint4(0, 0, 0, 0);
        int gr = rb + row;
        if (gr < N_NODES) v = *(const uint4*)&Hm[gr * 64 + k8 * 8];
        *(uint4*)&As[row][k8 * 8] = v;
    }
    int w = t >> 6, l = t & 63;
    int wr = (w >> 1) * 32, wc = (w & 1) * 32;
    int lr = l & 15, lk = (l >> 4) * 8;
    int drow = (l >> 4) * 4;
    int dcol = l & 15;
    for (int cb8 = 0; cb8 < 8; cb8++) {
        int cb = cb8 * 64;
        __syncthreads();
        #pragma unroll
        for (int i = 0; i < 2; i++) {
            int lin = t + i * 256;
            int n = lin >> 3;
            int k8 = lin & 7;
            *(uint4*)&Bs[n][k8 * 8] = *(const uint4*)&W2t[(cb + n) * 64 + k8 * 8];
        }
        __syncthreads();
        f32x4 c00 = {0.f,0.f,0.f,0.f}, c01 = {0.f,0.f,0.f,0.f};
        f32x4 c10 = {0.f,0.f,0.f,0.f}, c11 = {0.f,0.f,0.f,0.f};
        #pragma unroll
        for (int kk = 0; kk < 64; kk += 32) {
            short8 a0 = *(const short8*)&As[wr + lr][kk + lk];
            short8 a1 = *(const short8*)&As[wr + 16 + lr][kk + lk];
            short8 b0 = *(const short8*)&Bs[wc + lr][kk + lk];
            short8 b1 = *(const short8*)&Bs[wc + 16 + lr][kk + lk];
            c00 = __builtin_amdgcn_mfma_f32_16x16x32_bf16(a0, b0, c00, 0, 0, 0);
            c01 = __builtin_amdgcn_mfma_f32_16x16x32_bf16(a0, b1, c01, 0, 0, 0);
            c10 = __builtin_amdgcn_mfma_f32_16x16x32_bf16(a1, b0, c10, 0, 0, 0);
            c11 = __builtin_amdgcn_mfma_f32_16x16x32_bf16(a1, b1, c11, 0, 0, 0);
        }
        f32x4 cc[2][2] = {{c00, c01}, {c10, c11}};
        #pragma unroll
        for (int i = 0; i < 2; i++)
            #pragma unroll
            for (int j = 0; j < 2; j++)
                #pragma unroll
                for (int rg = 0; rg < 4; rg++) {
                    int gr = rb + wr + i * 16 + drow + rg;
                    int gc = cb + wc + j * 16 + dcol;
                    if (gr >= N_NODES) continue;
                    float v = cc[i][j][rg] + bcat[gc];
                    unsigned short h = f2bf(v);
                    if (gc < 128) Qb[gr * 128 + gc] = h;
                    else if (gc < 256) Kb[gr * 128 + (gc - 128)] = h;
                    else if (gc < 384) Vb[gr * 128 + (gc - 256)] = h;
                    else Sb[gr * 128 + (gc - 384)] = h;
                }
    }
}

// ---------------- fused attention + skip + classifier: one wave per dst node, unroll 4 ----------------
// softmax without max-subtraction (shift-invariant; scores are O(0.1) here)
__global__ __launch_bounds__(256) void attn_kernel(const unsigned short* __restrict__ Qb,
                                                   const unsigned short* __restrict__ Kb,
                                                   const unsigned short* __restrict__ Vb,
                                                   const int* __restrict__ rs, const unsigned int* __restrict__ ep,
                                                   const unsigned short* __restrict__ Sb,
                                                   const float* __restrict__ Wf, const float* __restrict__ bfv,
                                                   float* __restrict__ out) {
    int lane = threadIdx.x & 63;
    int n = blockIdx.x * 4 + (threadIdx.x >> 6);
    if (n >= N_NODES) return;
    const unsigned* Qu = (const unsigned*)Qb;
    const unsigned* Ku = (const unsigned*)Kb;
    const unsigned* Vu = (const unsigned*)Vb;
    const unsigned* Su = (const unsigned*)Sb;
    unsigned qw = Qu[n * 64 + lane];
    const float qs = 0.17677669529663687f;  // 1/sqrt(32)
    float q0 = bf2f(qw & 0xFFFF) * qs, q1 = bf2f(qw >> 16) * qs;
    float wf0[7], wf1[7];
    #pragma unroll
    for (int j = 0; j < 7; j++) { wf0[j] = Wf[(2 * lane) * 7 + j]; wf1[j] = Wf[(2 * lane + 1) * 7 + j]; }
    float d = 0.f, o0 = 0.f, o1 = 0.f;
    int p0 = rs[n], p1 = rs[n + 1];
    for (int base = p0; base < p1; base += 64) {
        int pc = base + lane;
        int chunk = (pc < p1) ? (int)ep[pc] : 0;
        int cnt = min(64, p1 - base);
        int j = 0;
        for (; j + 3 < cnt; j += 4) {
            int e0 = __builtin_amdgcn_readlane(chunk, j);
            int e1 = __builtin_amdgcn_readlane(chunk, j + 1);
            int e2 = __builtin_amdgcn_readlane(chunk, j + 2);
            int e3 = __builtin_amdgcn_readlane(chunk, j + 3);
            int s0 = e0 & 0xFFFFF, s1 = e1 & 0xFFFFF, s2 = e2 & 0xFFFFF, s3 = e3 & 0xFFFFF;
            unsigned k0 = Ku[s0 * 64 + lane], k1 = Ku[s1 * 64 + lane];
            unsigned k2 = Ku[s2 * 64 + lane], k3 = Ku[s3 * 64 + lane];
            unsigned v0 = Vu[s0 * 64 + lane], v1 = Vu[s1 * 64 + lane];
            unsigned v2 = Vu[s2 * 64 + lane], v3 = Vu[s3 * 64 + lane];
            float d0 = q0 * bf2f(k0 & 0xFFFF) + q1 * bf2f(k0 >> 16);
            float d1 = q0 * bf2f(k1 & 0xFFFF) + q1 * bf2f(k1 >> 16);
            float d2 = q0 * bf2f(k2 & 0xFFFF) + q1 * bf2f(k2 >> 16);
            float d3 = q0 * bf2f(k3 & 0xFFFF) + q1 * bf2f(k3 >> 16);
            d0 += __shfl_xor(d0, 1); d1 += __shfl_xor(d1, 1); d2 += __shfl_xor(d2, 1); d3 += __shfl_xor(d3, 1);
            d0 += __shfl_xor(d0, 2); d1 += __shfl_xor(d1, 2); d2 += __shfl_xor(d2, 2); d3 += __shfl_xor(d3, 2);
            d0 += __shfl_xor(d0, 4); d1 += __shfl_xor(d1, 4); d2 += __shfl_xor(d2, 4); d3 += __shfl_xor(d3, 4);
            d0 += __shfl_xor(d0, 8); d1 += __shfl_xor(d1, 8); d2 += __shfl_xor(d2, 8); d3 += __shfl_xor(d3, 8);
            float w0 = __expf(d0), w1 = __expf(d1), w2 = __expf(d2), w3 = __expf(d3);
            d += (w0 + w1) + (w2 + w3);
            o0 += w0 * bf2f(v0 & 0xFFFF) + w1 * bf2f(v1 & 0xFFFF)
                + w2 * bf2f(v2 & 0xFFFF) + w3 * bf2f(v3 & 0xFFFF);
            o1 += w0 * bf2f(v0 >> 16) + w1 * bf2f(v1 >> 16)
                + w2 * bf2f(v2 >> 16) + w3 * bf2f(v3 >> 16);
        }
        for (; j < cnt; j++) {
            int e0 = __builtin_amdgcn_readlane(chunk, j);
            int s0 = e0 & 0xFFFFF;
            unsigned k0 = Ku[s0 * 64 + lane];
            unsigned v0 = Vu[s0 * 64 + lane];
            float d0 = q0 * bf2f(k0 & 0xFFFF) + q1 * bf2f(k0 >> 16);
            d0 += __shfl_xor(d0, 1);
            d0 += __shfl_xor(d0, 2);
            d0 += __shfl_xor(d0, 4);
            d0 += __shfl_xor(d0, 8);
            float w0 = __expf(d0);
            d += w0;
            o0 += w0 * bf2f(v0 & 0xFFFF);
            o1 += w0 * bf2f(v0 >> 16);
        }
    }
    float inv = (d > 0.f) ? 1.f / d : 0.f;
    unsigned sw = Su[n * 64 + lane];
    float r0 = fmaxf(bf2f(sw & 0xFFFF) + o0 * inv, 0.f);
    float r1 = fmaxf(bf2f(sw >> 16) + o1 * inv, 0.f);
    float acc[7];
    #pragma unroll
    for (int j = 0; j < 7; j++) acc[j] = r0 * wf0[j] + r1 * wf1[j];
    #pragma unroll
    for (int j = 0; j < 7; j++) {
        acc[j] += __shfl_xor(acc[j], 1);
        acc[j] += __shfl_xor(acc[j], 2);
        acc[j] += __shfl_xor(acc[j], 4);
        acc[j] += __shfl_xor(acc[j], 8);
        acc[j] += __shfl_xor(acc[j], 16);
        acc[j] += __shfl_xor(acc[j], 32);
    }
    if (lane == 0) {
        #pragma unroll
        for (int j = 0; j < 7; j++) out[n * 7 + j] = acc[j] + bfv[j];
    }
}

extern "C" void kernel_launch(void* const* d_in, const int* in_sizes, int n_in,
                              void* d_out, int out_size, void* d_ws, size_t ws_size,
                              hipStream_t stream) {
    const float* x     = (const float*)d_in[0];
    const int*   ei    = (const int*)d_in[2];
    const int*   et    = (const int*)d_in[3];
    const float* Wrel  = (const float*)d_in[4];
    const float* Wroot = (const float*)d_in[5];
    const float* brg   = (const float*)d_in[6];
    const float* Wq    = (const float*)d_in[7];
    const float* bq    = (const float*)d_in[8];
    const float* Wk    = (const float*)d_in[9];
    const float* bk    = (const float*)d_in[10];
    const float* Wv    = (const float*)d_in[11];
    const float* bv    = (const float*)d_in[12];
    const float* Wsk   = (const float*)d_in[13];
    const float* bsk   = (const float*)d_in[14];
    const float* Wf    = (const float*)d_in[15];
    const float* bfv   = (const float*)d_in[16];
    float* out = (float*)d_out;

    // workspace layout (~123 MB):
    //  [0,       51.2M)  hr_all bf16 [N][256] (cols 192..255 = root); dead after rgcn
    //  [0,       76.8M)  Qb|Kb|Vb bf16 [N,128]x3 (Qb,Kb overlay hr_all)
    //  [76.8M,   89.6M)  Hm bf16 [N,64]
    //  [89.6M,  115.2M)  Sb (skip) bf16 [N,128]
    //  [115.2M, 121.6M)  ep u32 [E]
    //  then rs / deg+fill (contiguous memset) / part / W1t / W2t / bcat
    char* ws = (char*)d_ws;
    unsigned short* hr_all = (unsigned short*)(ws + 0);
    unsigned short* Qb     = (unsigned short*)(ws + 0);
    unsigned short* Kb     = (unsigned short*)(ws + 25600000);
    unsigned short* Vb     = (unsigned short*)(ws + 51200000);
    unsigned short* Hm     = (unsigned short*)(ws + 76800000);
    unsigned short* Sb     = (unsigned short*)(ws + 89600000);
    unsigned int*   ep     = (unsigned int*)(ws + 115200000);
    int*            rs     = (int*)(ws + 121600000);
    int*            deg    = (int*)(ws + 122000016);
    int*            fill   = (int*)(ws + 122400016);
    int*            part   = (int*)(ws + 122800016);
    unsigned short* W1t    = (unsigned short*)(ws + 122800528);
    unsigned short* W2t    = (unsigned short*)(ws + 122866064);
    float*          bcat   = (float*)(ws + 122931600);

    hipMemsetAsync(deg, 0, 2 * N_NODES * sizeof(int), stream);   // deg + fill contiguous

    repack_kernel<<<258, 256, 0, stream>>>(Wrel, Wroot, Wq, Wk, Wv, Wsk, bq, bk, bv, bsk, W1t, W2t, bcat);

    // CSR build by destination
    hist_kernel<<<N_EDGES / 256, 256, 0, stream>>>(ei, deg);
    scanA_kernel<<<98, 256, 0, stream>>>(deg, part);
    scanB_kernel<<<1, 1, 0, stream>>>(part, rs, 98);
    scanC_kernel<<<98, 256, 0, stream>>>(deg, part, rs);
    scatter_kernel<<<N_EDGES / 256, 256, 0, stream>>>(ei, et, rs, fill, ep);

    // RGCN
    gemm1_mfma<<<1563, 256, 0, stream>>>(x, W1t, hr_all);
    rgcn_kernel<<<25000, 256, 0, stream>>>(hr_all, brg, rs, ep, Hm);

    // TransformerConv
    gemm2_mfma<<<1563, 256, 0, stream>>>(Hm, W2t, bcat, Qb, Kb, Vb, Sb);
    attn_kernel<<<25000, 256, 0, stream>>>(Qb, Kb, Vb, rs, ep, Sb, Wf, bfv, out);
}

// Round 5
// 524.295 us; speedup vs baseline: 1.6694x; 1.0456x over previous
//
#include <hip/hip_runtime.h>
#include <math.h>

#define N_NODES 100000
#define N_EDGES 1600000

typedef short short8 __attribute__((ext_vector_type(8)));
typedef float f32x4 __attribute__((ext_vector_type(4)));

static __device__ __forceinline__ float bf2f(unsigned int u16) {
    return __uint_as_float(u16 << 16);
}
static __device__ __forceinline__ unsigned short f2bf(float f) {
    unsigned u = __float_as_uint(f);
    unsigned r = u + 0x7FFF + ((u >> 16) & 1);   // RTNE
    return (unsigned short)(r >> 16);
}
static __device__ __forceinline__ void unpack8(uint4 u, float* f) {
    f[0] = bf2f(u.x & 0xFFFF); f[1] = bf2f(u.x >> 16);
    f[2] = bf2f(u.y & 0xFFFF); f[3] = bf2f(u.y >> 16);
    f[4] = bf2f(u.z & 0xFFFF); f[5] = bf2f(u.z >> 16);
    f[6] = bf2f(u.w & 0xFFFF); f[7] = bf2f(u.w >> 16);
}
static __device__ __forceinline__ void unpack4(uint2 u, float* f) {
    f[0] = bf2f(u.x & 0xFFFF); f[1] = bf2f(u.x >> 16);
    f[2] = bf2f(u.y & 0xFFFF); f[3] = bf2f(u.y >> 16);
}

// ---------------- weight repack ----------------
__global__ void repack_kernel(const float* __restrict__ Wrel, const float* __restrict__ Wroot,
                              const float* __restrict__ Wq, const float* __restrict__ Wk,
                              const float* __restrict__ Wv, const float* __restrict__ Wsk,
                              const float* __restrict__ bq, const float* __restrict__ bk,
                              const float* __restrict__ bv, const float* __restrict__ bsk,
                              unsigned short* __restrict__ W1t, unsigned short* __restrict__ W2t,
                              float* __restrict__ bcat) {
    int idx = blockIdx.x * 256 + threadIdx.x;
    if (idx < 128 * 256) {
        int k = idx >> 8, c = idx & 255;
        float v;
        if (c < 192) { int r = c >> 6, cc = c & 63; v = Wrel[r * 8192 + k * 64 + cc]; }
        else v = Wroot[k * 64 + (c - 192)];
        W1t[c * 128 + k] = f2bf(v);
    }
    int i2 = idx - 128 * 256;
    if (i2 >= 0 && i2 < 64 * 512) {
        int k = i2 >> 9, c = i2 & 511;
        float v;
        if (c < 128) v = Wq[k * 128 + c];
        else if (c < 256) v = Wk[k * 128 + c - 128];
        else if (c < 384) v = Wv[k * 128 + c - 256];
        else v = Wsk[k * 128 + c - 384];
        W2t[c * 64 + k] = f2bf(v);
    }
    int i3 = idx - 128 * 256 - 64 * 512;
    if (i3 >= 0 && i3 < 512) {
        float v;
        if (i3 < 128) v = bq[i3];
        else if (i3 < 256) v = bk[i3 - 128];
        else if (i3 < 384) v = bv[i3 - 256];
        else v = bsk[i3 - 384];
        bcat[i3] = v;
    }
}

// ---------------- CSR build (per-relation counts) ----------------
__global__ void hist_kernel(const int* __restrict__ ei, const int* __restrict__ et,
                            int* __restrict__ cntr) {
    int e = blockIdx.x * 256 + threadIdx.x;
    if (e < N_EDGES) atomicAdd(&cntr[et[e] * N_NODES + ei[N_EDGES + e]], 1);
}

__global__ void scanA_kernel(const int* __restrict__ cntr, int* __restrict__ part) {
    __shared__ int wsum[4];
    int t = threadIdx.x;
    int base = blockIdx.x * 1024 + t * 4;
    int s = 0;
    for (int i = 0; i < 4; i++) {
        int idx = base + i;
        if (idx < N_NODES) s += cntr[idx] + cntr[N_NODES + idx] + cntr[2 * N_NODES + idx];
    }
    for (int off = 1; off < 64; off <<= 1) s += __shfl_xor(s, off);
    if ((t & 63) == 0) wsum[t >> 6] = s;
    __syncthreads();
    if (t == 0) part[blockIdx.x] = wsum[0] + wsum[1] + wsum[2] + wsum[3];
}

__global__ void scanC_kernel(const int* __restrict__ cntr, const int* __restrict__ part,
                             int* __restrict__ rs) {
    __shared__ int wsum[4];
    __shared__ int ws2[4];
    int t = threadIdx.x;
    int lane = t & 63;
    int base = blockIdx.x * 1024 + t * 4;
    int v[4]; int tsum = 0;
    for (int i = 0; i < 4; i++) {
        int idx = base + i;
        v[i] = (idx < N_NODES) ? (cntr[idx] + cntr[N_NODES + idx] + cntr[2 * N_NODES + idx]) : 0;
        tsum += v[i];
    }
    // block offset = sum of part[0..bid)
    int p = (t < blockIdx.x) ? part[t] : 0;
    for (int off = 1; off < 64; off <<= 1) p += __shfl_xor(p, off);
    if (lane == 0) ws2[t >> 6] = p;
    // wave inclusive scan of tsum
    int x = tsum;
    for (int off = 1; off < 64; off <<= 1) { int y = __shfl_up(x, off); if (lane >= off) x += y; }
    if (lane == 63) wsum[t >> 6] = x;
    __syncthreads();
    if (t == 0) { int run = 0; for (int w = 0; w < 4; w++) { int tmp = wsum[w]; wsum[w] = run; run += tmp; } }
    __syncthreads();
    int bofs = ws2[0] + ws2[1] + ws2[2] + ws2[3];
    int excl = x - tsum + wsum[t >> 6] + bofs;
    for (int i = 0; i < 4; i++) {
        int idx = base + i;
        if (idx < N_NODES) rs[idx] = excl;
        excl += v[i];
    }
    if (blockIdx.x == 0 && t == 0) rs[N_NODES] = N_EDGES;
}

// scatter: ep = src*4 + r ; epw = 1/cnt_r(dst)
__global__ void scatter_kernel(const int* __restrict__ ei, const int* __restrict__ et,
                               const int* __restrict__ rs, const int* __restrict__ cntr,
                               int* __restrict__ fill,
                               unsigned int* __restrict__ ep, float* __restrict__ epw) {
    int e = blockIdx.x * 256 + threadIdx.x;
    if (e >= N_EDGES) return;
    int src = ei[e], dst = ei[N_EDGES + e], r = et[e];
    int pos = rs[dst] + atomicAdd(&fill[dst], 1);
    int c = cntr[r * N_NODES + dst];
    ep[pos] = ((unsigned)src << 2) | (unsigned)r;
    epw[pos] = 1.f / (float)c;
}

// ---------------- GEMM1 (MFMA bf16): X[N,128] @ W1[128,256] -> hr_all bf16 [N][256] ----------------
__global__ __launch_bounds__(256) void gemm1_mfma(const float* __restrict__ X,
                                                  const unsigned short* __restrict__ W1t,
                                                  unsigned short* __restrict__ hr_all) {
    __shared__ unsigned short As[64][136];
    __shared__ unsigned short Bs[64][136];
    int t = threadIdx.x;
    int rb = blockIdx.x * 64;
    #pragma unroll
    for (int i = 0; i < 8; i++) {
        int lin = t + i * 256;
        int row = lin >> 5;
        int c4 = lin & 31;
        float4 v = make_float4(0.f, 0.f, 0.f, 0.f);
        int gr = rb + row;
        if (gr < N_NODES) v = *(const float4*)&X[gr * 128 + c4 * 4];
        unsigned w0 = (unsigned)f2bf(v.x) | ((unsigned)f2bf(v.y) << 16);
        unsigned w1 = (unsigned)f2bf(v.z) | ((unsigned)f2bf(v.w) << 16);
        *(uint2*)&As[row][c4 * 4] = make_uint2(w0, w1);
    }
    int w = t >> 6, l = t & 63;
    int wr = (w >> 1) * 32, wc = (w & 1) * 32;
    int lr = l & 15, lk = (l >> 4) * 8;
    int drow = (l >> 4) * 4;
    int dcol = l & 15;
    for (int cb4 = 0; cb4 < 4; cb4++) {
        int cb = cb4 * 64;
        __syncthreads();
        #pragma unroll
        for (int i = 0; i < 4; i++) {
            int lin = t + i * 256;
            int n = lin >> 4;
            int k8 = lin & 15;
            *(uint4*)&Bs[n][k8 * 8] = *(const uint4*)&W1t[(cb + n) * 128 + k8 * 8];
        }
        __syncthreads();
        f32x4 c00 = {0.f,0.f,0.f,0.f}, c01 = {0.f,0.f,0.f,0.f};
        f32x4 c10 = {0.f,0.f,0.f,0.f}, c11 = {0.f,0.f,0.f,0.f};
        #pragma unroll
        for (int kk = 0; kk < 128; kk += 32) {
            short8 a0 = *(const short8*)&As[wr + lr][kk + lk];
            short8 a1 = *(const short8*)&As[wr + 16 + lr][kk + lk];
            short8 b0 = *(const short8*)&Bs[wc + lr][kk + lk];
            short8 b1 = *(const short8*)&Bs[wc + 16 + lr][kk + lk];
            c00 = __builtin_amdgcn_mfma_f32_16x16x32_bf16(a0, b0, c00, 0, 0, 0);
            c01 = __builtin_amdgcn_mfma_f32_16x16x32_bf16(a0, b1, c01, 0, 0, 0);
            c10 = __builtin_amdgcn_mfma_f32_16x16x32_bf16(a1, b0, c10, 0, 0, 0);
            c11 = __builtin_amdgcn_mfma_f32_16x16x32_bf16(a1, b1, c11, 0, 0, 0);
        }
        f32x4 cc[2][2] = {{c00, c01}, {c10, c11}};
        #pragma unroll
        for (int i = 0; i < 2; i++)
            #pragma unroll
            for (int j = 0; j < 2; j++)
                #pragma unroll
                for (int rg = 0; rg < 4; rg++) {
                    int gr = rb + wr + i * 16 + drow + rg;
                    int gc = cb + wc + j * 16 + dcol;
                    if (gr < N_NODES) hr_all[gr * 256 + gc] = f2bf(cc[i][j][rg]);
                }
    }
}

// ---------------- RGCN aggregate: 4 edges/wave, 16 lanes/edge, weighted sum ----------------
__global__ __launch_bounds__(256) void rgcn_kernel(const unsigned short* __restrict__ hr,
                                                   const float* __restrict__ brg, const int* __restrict__ rs,
                                                   const unsigned int* __restrict__ ep,
                                                   const float* __restrict__ epw,
                                                   unsigned short* __restrict__ Hm) {
    int t = threadIdx.x, lane = t & 63;
    int n = blockIdx.x * 4 + (t >> 6);
    if (n >= N_NODES) return;
    int slot = lane >> 4, pos = lane & 15;
    const uint2* H2 = (const uint2*)hr;
    float a0 = 0.f, a1 = 0.f, a2 = 0.f, a3 = 0.f;
    int p0 = rs[n], p1 = rs[n + 1];
    for (int base = p0; base < p1; base += 64) {
        int pc = base + lane;
        unsigned chunk = (pc < p1) ? ep[pc] : 0u;
        float wch = (pc < p1) ? epw[pc] : 0.f;
        int cnt = min(64, p1 - base);
        for (int g0 = 0; g0 < cnt; g0 += 8) {
            int iA = g0 + slot, iB = iA + 4;
            unsigned eA = (unsigned)__shfl((int)chunk, iA);
            unsigned eB = (unsigned)__shfl((int)chunk, iB);
            float wA = __shfl(wch, iA);      // 0 for invalid edges
            float wB = __shfl(wch, iB);
            uint2 hA = H2[eA * 16 + pos];    // row = (src*4+r)*64 dims
            uint2 hB = H2[eB * 16 + pos];
            float f[4];
            unpack4(hA, f);
            a0 += wA * f[0]; a1 += wA * f[1]; a2 += wA * f[2]; a3 += wA * f[3];
            unpack4(hB, f);
            a0 += wB * f[0]; a1 += wB * f[1]; a2 += wB * f[2]; a3 += wB * f[3];
        }
    }
    a0 += __shfl_xor(a0, 16); a0 += __shfl_xor(a0, 32);
    a1 += __shfl_xor(a1, 16); a1 += __shfl_xor(a1, 32);
    a2 += __shfl_xor(a2, 16); a2 += __shfl_xor(a2, 32);
    a3 += __shfl_xor(a3, 16); a3 += __shfl_xor(a3, 32);
    uint2 rt = H2[(n * 4 + 3) * 16 + pos];   // root block (r=3 slot of hr row)
    float rtf[4]; unpack4(rt, rtf);
    float4 bb = ((const float4*)brg)[pos];
    float h0 = fmaxf(rtf[0] + bb.x + a0, 0.f);
    float h1 = fmaxf(rtf[1] + bb.y + a1, 0.f);
    float h2 = fmaxf(rtf[2] + bb.z + a2, 0.f);
    float h3 = fmaxf(rtf[3] + bb.w + a3, 0.f);
    if (slot == 0) {
        uint2 wv;
        wv.x = (unsigned)f2bf(h0) | ((unsigned)f2bf(h1) << 16);
        wv.y = (unsigned)f2bf(h2) | ((unsigned)f2bf(h3) << 16);
        ((uint2*)Hm)[n * 16 + pos] = wv;
    }
}

// ---------------- GEMM2 (MFMA bf16): Hm[N,64] @ W2[64,512] + bcat -> Qb,Kb,Vb,Sb bf16 [N,128] ----------------
__global__ __launch_bounds__(256) void gemm2_mfma(const unsigned short* __restrict__ Hm,
                                                  const unsigned short* __restrict__ W2t,
                                                  const float* __restrict__ bcat,
                                                  unsigned short* __restrict__ Qb, unsigned short* __restrict__ Kb,
                                                  unsigned short* __restrict__ Vb, unsigned short* __restrict__ Sb) {
    __shared__ unsigned short As[64][72];
    __shared__ unsigned short Bs[64][72];
    int t = threadIdx.x;
    int rb = blockIdx.x * 64;
    #pragma unroll
    for (int i = 0; i < 2; i++) {
        int lin = t + i * 256;
        int row = lin >> 3;
        int k8 = lin & 7;
        uint4 v = make_uint4(0, 0, 0, 0);
        int gr = rb + row;
        if (gr < N_NODES) v = *(const uint4*)&Hm[gr * 64 + k8 * 8];
        *(uint4*)&As[row][k8 * 8] = v;
    }
    int w = t >> 6, l = t & 63;
    int wr = (w >> 1) * 32, wc = (w & 1) * 32;
    int lr = l & 15, lk = (l >> 4) * 8;
    int drow = (l >> 4) * 4;
    int dcol = l & 15;
    for (int cb8 = 0; cb8 < 8; cb8++) {
        int cb = cb8 * 64;
        __syncthreads();
        #pragma unroll
        for (int i = 0; i < 2; i++) {
            int lin = t + i * 256;
            int n = lin >> 3;
            int k8 = lin & 7;
            *(uint4*)&Bs[n][k8 * 8] = *(const uint4*)&W2t[(cb + n) * 64 + k8 * 8];
        }
        __syncthreads();
        f32x4 c00 = {0.f,0.f,0.f,0.f}, c01 = {0.f,0.f,0.f,0.f};
        f32x4 c10 = {0.f,0.f,0.f,0.f}, c11 = {0.f,0.f,0.f,0.f};
        #pragma unroll
        for (int kk = 0; kk < 64; kk += 32) {
            short8 a0 = *(const short8*)&As[wr + lr][kk + lk];
            short8 a1 = *(const short8*)&As[wr + 16 + lr][kk + lk];
            short8 b0 = *(const short8*)&Bs[wc + lr][kk + lk];
            short8 b1 = *(const short8*)&Bs[wc + 16 + lr][kk + lk];
            c00 = __builtin_amdgcn_mfma_f32_16x16x32_bf16(a0, b0, c00, 0, 0, 0);
            c01 = __builtin_amdgcn_mfma_f32_16x16x32_bf16(a0, b1, c01, 0, 0, 0);
            c10 = __builtin_amdgcn_mfma_f32_16x16x32_bf16(a1, b0, c10, 0, 0, 0);
            c11 = __builtin_amdgcn_mfma_f32_16x16x32_bf16(a1, b1, c11, 0, 0, 0);
        }
        f32x4 cc[2][2] = {{c00, c01}, {c10, c11}};
        #pragma unroll
        for (int i = 0; i < 2; i++)
            #pragma unroll
            for (int j = 0; j < 2; j++)
                #pragma unroll
                for (int rg = 0; rg < 4; rg++) {
                    int gr = rb + wr + i * 16 + drow + rg;
                    int gc = cb + wc + j * 16 + dcol;
                    if (gr >= N_NODES) continue;
                    float v = cc[i][j][rg] + bcat[gc];
                    unsigned short h = f2bf(v);
                    if (gc < 128) Qb[gr * 128 + gc] = h;
                    else if (gc < 256) Kb[gr * 128 + (gc - 128)] = h;
                    else if (gc < 384) Vb[gr * 128 + (gc - 256)] = h;
                    else Sb[gr * 128 + (gc - 384)] = h;
                }
    }
}

// ---------------- fused attention + skip + classifier: 4 edges/wave, 16 lanes/edge ----------------
__global__ __launch_bounds__(256) void attn_kernel(const unsigned short* __restrict__ Qb,
                                                   const unsigned short* __restrict__ Kb,
                                                   const unsigned short* __restrict__ Vb,
                                                   const int* __restrict__ rs, const unsigned int* __restrict__ ep,
                                                   const unsigned short* __restrict__ Sb,
                                                   const float* __restrict__ Wf, const float* __restrict__ bfv,
                                                   float* __restrict__ out) {
    int t = threadIdx.x, lane = t & 63;
    int n = blockIdx.x * 4 + (t >> 6);
    if (n >= N_NODES) return;
    int slot = lane >> 4, pos = lane & 15;         // lane covers dims pos*8..pos*8+7 of edge-slot `slot`
    const uint4* K4 = (const uint4*)Kb;
    const uint4* V4 = (const uint4*)Vb;
    const float qs = 0.17677669529663687f;          // 1/sqrt(32)
    uint4 qv = ((const uint4*)Qb)[n * 16 + pos];
    float q[8]; unpack8(qv, q);
    #pragma unroll
    for (int i = 0; i < 8; i++) q[i] *= qs;
    float o[8] = {0.f,0.f,0.f,0.f,0.f,0.f,0.f,0.f};
    float d = 0.f;
    int p0 = rs[n], p1 = rs[n + 1];
    for (int base = p0; base < p1; base += 64) {
        int pc = base + lane;
        unsigned chunk = (pc < p1) ? ep[pc] : 0u;
        int cnt = min(64, p1 - base);
        for (int g0 = 0; g0 < cnt; g0 += 8) {
            int iA = g0 + slot, iB = iA + 4;
            unsigned eA = (unsigned)__shfl((int)chunk, iA);
            unsigned eB = (unsigned)__shfl((int)chunk, iB);
            int sA = (int)(eA >> 2), sB = (int)(eB >> 2);
            uint4 kA = K4[sA * 16 + pos];
            uint4 vA = V4[sA * 16 + pos];
            uint4 kB = K4[sB * 16 + pos];
            uint4 vB = V4[sB * 16 + pos];
            float kf[8], vf[8];
            unpack8(kA, kf);
            float dotA = q[0]*kf[0] + q[1]*kf[1] + q[2]*kf[2] + q[3]*kf[3]
                       + q[4]*kf[4] + q[5]*kf[5] + q[6]*kf[6] + q[7]*kf[7];
            dotA += __shfl_xor(dotA, 1);
            dotA += __shfl_xor(dotA, 2);          // per-head (4-lane) dot
            float wA = __expf(dotA);
            wA = (iA < cnt) ? wA : 0.f;
            unpack8(kB, kf);
            float dotB = q[0]*kf[0] + q[1]*kf[1] + q[2]*kf[2] + q[3]*kf[3]
                       + q[4]*kf[4] + q[5]*kf[5] + q[6]*kf[6] + q[7]*kf[7];
            dotB += __shfl_xor(dotB, 1);
            dotB += __shfl_xor(dotB, 2);
            float wB = __expf(dotB);
            wB = (iB < cnt) ? wB : 0.f;
            d += wA + wB;
            unpack8(vA, vf);
            #pragma unroll
            for (int i = 0; i < 8; i++) o[i] += wA * vf[i];
            unpack8(vB, vf);
            #pragma unroll
            for (int i = 0; i < 8; i++) o[i] += wB * vf[i];
        }
    }
    // combine the 4 edge-slots
    d += __shfl_xor(d, 16); d += __shfl_xor(d, 32);
    #pragma unroll
    for (int i = 0; i < 8; i++) { o[i] += __shfl_xor(o[i], 16); o[i] += __shfl_xor(o[i], 32); }
    float inv = (d > 0.f) ? 1.f / d : 0.f;
    uint4 sv = ((const uint4*)Sb)[n * 16 + pos];
    float sf[8]; unpack8(sv, sf);
    float rf[8];
    #pragma unroll
    for (int i = 0; i < 8; i++) rf[i] = fmaxf(sf[i] + o[i] * inv, 0.f);
    // classifier: slot s handles dims pos*8 + s*2 + {0,1}  (each dim exactly once across the wave)
    float rr0 = (slot == 0) ? rf[0] : (slot == 1) ? rf[2] : (slot == 2) ? rf[4] : rf[6];
    float rr1 = (slot == 0) ? rf[1] : (slot == 1) ? rf[3] : (slot == 2) ? rf[5] : rf[7];
    int gd = pos * 8 + slot * 2;
    float acc[7];
    #pragma unroll
    for (int j = 0; j < 7; j++) acc[j] = rr0 * Wf[gd * 7 + j] + rr1 * Wf[gd * 7 + 7 + j];
    #pragma unroll
    for (int j = 0; j < 7; j++) {
        acc[j] += __shfl_xor(acc[j], 1);
        acc[j] += __shfl_xor(acc[j], 2);
        acc[j] += __shfl_xor(acc[j], 4);
        acc[j] += __shfl_xor(acc[j], 8);
        acc[j] += __shfl_xor(acc[j], 16);
        acc[j] += __shfl_xor(acc[j], 32);
    }
    if (lane == 0) {
        #pragma unroll
        for (int j = 0; j < 7; j++) out[n * 7 + j] = acc[j] + bfv[j];
    }
}

extern "C" void kernel_launch(void* const* d_in, const int* in_sizes, int n_in,
                              void* d_out, int out_size, void* d_ws, size_t ws_size,
                              hipStream_t stream) {
    const float* x     = (const float*)d_in[0];
    const int*   ei    = (const int*)d_in[2];
    const int*   et    = (const int*)d_in[3];
    const float* Wrel  = (const float*)d_in[4];
    const float* Wroot = (const float*)d_in[5];
    const float* brg   = (const float*)d_in[6];
    const float* Wq    = (const float*)d_in[7];
    const float* bq    = (const float*)d_in[8];
    const float* Wk    = (const float*)d_in[9];
    const float* bk    = (const float*)d_in[10];
    const float* Wv    = (const float*)d_in[11];
    const float* bv    = (const float*)d_in[12];
    const float* Wsk   = (const float*)d_in[13];
    const float* bsk   = (const float*)d_in[14];
    const float* Wf    = (const float*)d_in[15];
    const float* bfv   = (const float*)d_in[16];
    float* out = (float*)d_out;

    // workspace layout (~130.2 MB):
    //  [0,       51.2M)  hr_all bf16 [N][256] (block r of row = rel transform, block 3 = root); dead after rgcn
    //  [0,       76.8M)  Qb|Kb|Vb bf16 [N,128]x3 (Qb,Kb overlay hr_all)
    //  [76.8M,  102.4M)  Sb (skip) bf16 [N,128]
    //  [102.4M, 115.2M)  Hm bf16 [N,64]
    //  [115.2M, 121.6M)  ep u32 [E]  (src*4+r)
    //  [121.6M, 128.0M)  epw f32 [E] (1/cnt_r(dst))
    //  then rs / cntr+fill (contiguous memset) / part / W1t / W2t / bcat
    char* ws = (char*)d_ws;
    unsigned short* hr_all = (unsigned short*)(ws + 0);
    unsigned short* Qb     = (unsigned short*)(ws + 0);
    unsigned short* Kb     = (unsigned short*)(ws + 25600000);
    unsigned short* Vb     = (unsigned short*)(ws + 51200000);
    unsigned short* Sb     = (unsigned short*)(ws + 76800000);
    unsigned short* Hm     = (unsigned short*)(ws + 102400000);
    unsigned int*   ep     = (unsigned int*)(ws + 115200000);
    float*          epw    = (float*)(ws + 121600000);
    int*            rs     = (int*)(ws + 128000000);
    int*            cntr   = (int*)(ws + 128400016);
    int*            fill   = (int*)(ws + 129600016);
    int*            part   = (int*)(ws + 130000016);
    unsigned short* W1t    = (unsigned short*)(ws + 130000528);
    unsigned short* W2t    = (unsigned short*)(ws + 130066064);
    float*          bcat   = (float*)(ws + 130131600);

    hipMemsetAsync(cntr, 0, 4 * N_NODES * sizeof(int), stream);   // cntr (3N) + fill (N) contiguous

    repack_kernel<<<258, 256, 0, stream>>>(Wrel, Wroot, Wq, Wk, Wv, Wsk, bq, bk, bv, bsk, W1t, W2t, bcat);

    // CSR build by destination
    hist_kernel<<<N_EDGES / 256, 256, 0, stream>>>(ei, et, cntr);
    scanA_kernel<<<98, 256, 0, stream>>>(cntr, part);
    scanC_kernel<<<98, 256, 0, stream>>>(cntr, part, rs);
    scatter_kernel<<<N_EDGES / 256, 256, 0, stream>>>(ei, et, rs, cntr, fill, ep, epw);

    // RGCN
    gemm1_mfma<<<1563, 256, 0, stream>>>(x, W1t, hr_all);
    rgcn_kernel<<<25000, 256, 0, stream>>>(hr_all, brg, rs, ep, epw, Hm);

    // TransformerConv
    gemm2_mfma<<<1563, 256, 0, stream>>>(Hm, W2t, bcat, Qb, Kb, Vb, Sb);
    attn_kernel<<<25000, 256, 0, stream>>>(Qb, Kb, Vb, rs, ep, Sb, Wf, bfv, out);
}

// Round 6
// 504.471 us; speedup vs baseline: 1.7350x; 1.0393x over previous
//
#include <hip/hip_runtime.h>
#include <math.h>

#define N_NODES 100000
#define N_EDGES 1600000

typedef short short8 __attribute__((ext_vector_type(8)));
typedef float f32x4 __attribute__((ext_vector_type(4)));
typedef float f32x2 __attribute__((ext_vector_type(2)));
typedef _Float16 h2 __attribute__((ext_vector_type(2)));

// 1/sqrt(32) * log2(e)  (fold softmax scale + exp2 conversion into Q)
#define QSC 0.25503540f

static __device__ __forceinline__ float bf2f(unsigned int u16) {
    return __uint_as_float(u16 << 16);
}
static __device__ __forceinline__ unsigned short f2bf(float f) {
    unsigned u = __float_as_uint(f);
    unsigned r = u + 0x7FFF + ((u >> 16) & 1);   // RTNE
    return (unsigned short)(r >> 16);
}
static __device__ __forceinline__ f32x2 bfpair(unsigned u) {
    f32x2 r;
    r.x = __uint_as_float(u << 16);
    r.y = __uint_as_float(u & 0xFFFF0000u);
    return r;
}
static __device__ __forceinline__ float dot8h(const h2* q, uint4 k) {
    h2 s = q[0] * __builtin_bit_cast(h2, k.x);
    s += q[1] * __builtin_bit_cast(h2, k.y);
    s += q[2] * __builtin_bit_cast(h2, k.z);
    s += q[3] * __builtin_bit_cast(h2, k.w);
    return (float)s.x + (float)s.y;
}
static __device__ __forceinline__ void pv8h(h2* o, float w, uint4 v) {
    _Float16 wh = (_Float16)w;
    o[0] += wh * __builtin_bit_cast(h2, v.x);
    o[1] += wh * __builtin_bit_cast(h2, v.y);
    o[2] += wh * __builtin_bit_cast(h2, v.z);
    o[3] += wh * __builtin_bit_cast(h2, v.w);
}

// ---------------- weight repack ----------------
__global__ void repack_kernel(const float* __restrict__ Wrel, const float* __restrict__ Wroot,
                              const float* __restrict__ Wq, const float* __restrict__ Wk,
                              const float* __restrict__ Wv, const float* __restrict__ Wsk,
                              const float* __restrict__ bq, const float* __restrict__ bk,
                              const float* __restrict__ bv, const float* __restrict__ bsk,
                              unsigned short* __restrict__ W1t, unsigned short* __restrict__ W2t,
                              float* __restrict__ bcat) {
    int idx = blockIdx.x * 256 + threadIdx.x;
    if (idx < 128 * 256) {
        int k = idx >> 8, c = idx & 255;
        float v;
        if (c < 192) { int r = c >> 6, cc = c & 63; v = Wrel[r * 8192 + k * 64 + cc]; }
        else v = Wroot[k * 64 + (c - 192)];
        W1t[c * 128 + k] = f2bf(v);
    }
    int i2 = idx - 128 * 256;
    if (i2 >= 0 && i2 < 64 * 512) {
        int k = i2 >> 9, c = i2 & 511;
        float v;
        if (c < 128) v = Wq[k * 128 + c];
        else if (c < 256) v = Wk[k * 128 + c - 128];
        else if (c < 384) v = Wv[k * 128 + c - 256];
        else v = Wsk[k * 128 + c - 384];
        W2t[c * 64 + k] = f2bf(v);
    }
    int i3 = idx - 128 * 256 - 64 * 512;
    if (i3 >= 0 && i3 < 512) {
        float v;
        if (i3 < 128) v = bq[i3];
        else if (i3 < 256) v = bk[i3 - 128];
        else if (i3 < 384) v = bv[i3 - 256];
        else v = bsk[i3 - 384];
        bcat[i3] = v;
    }
}

// ---------------- CSR build (per-relation counts) ----------------
__global__ void hist_kernel(const int* __restrict__ ei, const int* __restrict__ et,
                            int* __restrict__ cntr) {
    int e = blockIdx.x * 256 + threadIdx.x;
    if (e < N_EDGES) atomicAdd(&cntr[et[e] * N_NODES + ei[N_EDGES + e]], 1);
}

__global__ void scanA_kernel(const int* __restrict__ cntr, int* __restrict__ part) {
    __shared__ int wsum[4];
    int t = threadIdx.x;
    int base = blockIdx.x * 1024 + t * 4;
    int s = 0;
    for (int i = 0; i < 4; i++) {
        int idx = base + i;
        if (idx < N_NODES) s += cntr[idx] + cntr[N_NODES + idx] + cntr[2 * N_NODES + idx];
    }
    for (int off = 1; off < 64; off <<= 1) s += __shfl_xor(s, off);
    if ((t & 63) == 0) wsum[t >> 6] = s;
    __syncthreads();
    if (t == 0) part[blockIdx.x] = wsum[0] + wsum[1] + wsum[2] + wsum[3];
}

__global__ void scanC_kernel(const int* __restrict__ cntr, const int* __restrict__ part,
                             int* __restrict__ rs) {
    __shared__ int wsum[4];
    __shared__ int ws2[4];
    int t = threadIdx.x;
    int lane = t & 63;
    int base = blockIdx.x * 1024 + t * 4;
    int v[4]; int tsum = 0;
    for (int i = 0; i < 4; i++) {
        int idx = base + i;
        v[i] = (idx < N_NODES) ? (cntr[idx] + cntr[N_NODES + idx] + cntr[2 * N_NODES + idx]) : 0;
        tsum += v[i];
    }
    int p = (t < blockIdx.x) ? part[t] : 0;
    for (int off = 1; off < 64; off <<= 1) p += __shfl_xor(p, off);
    if (lane == 0) ws2[t >> 6] = p;
    int x = tsum;
    for (int off = 1; off < 64; off <<= 1) { int y = __shfl_up(x, off); if (lane >= off) x += y; }
    if (lane == 63) wsum[t >> 6] = x;
    __syncthreads();
    if (t == 0) { int run = 0; for (int w = 0; w < 4; w++) { int tmp = wsum[w]; wsum[w] = run; run += tmp; } }
    __syncthreads();
    int bofs = ws2[0] + ws2[1] + ws2[2] + ws2[3];
    int excl = x - tsum + wsum[t >> 6] + bofs;
    for (int i = 0; i < 4; i++) {
        int idx = base + i;
        if (idx < N_NODES) rs[idx] = excl;
        excl += v[i];
    }
    if (blockIdx.x == 0 && t == 0) rs[N_NODES] = N_EDGES;
}

// scatter: ep = src*4 + r ; epw = 1/cnt_r(dst)
__global__ void scatter_kernel(const int* __restrict__ ei, const int* __restrict__ et,
                               const int* __restrict__ rs, const int* __restrict__ cntr,
                               int* __restrict__ fill,
                               unsigned int* __restrict__ ep, float* __restrict__ epw) {
    int e = blockIdx.x * 256 + threadIdx.x;
    if (e >= N_EDGES) return;
    int src = ei[e], dst = ei[N_EDGES + e], r = et[e];
    int pos = rs[dst] + atomicAdd(&fill[dst], 1);
    int c = cntr[r * N_NODES + dst];
    ep[pos] = ((unsigned)src << 2) | (unsigned)r;
    epw[pos] = 1.f / (float)c;
}

// ---------------- GEMM1 (MFMA bf16): X[N,128] @ W1[128,256] -> hr_all bf16 [N][256] ----------------
__global__ __launch_bounds__(256) void gemm1_mfma(const float* __restrict__ X,
                                                  const unsigned short* __restrict__ W1t,
                                                  unsigned short* __restrict__ hr_all) {
    __shared__ unsigned short As[64][136];
    __shared__ unsigned short Bs[64][136];
    int t = threadIdx.x;
    int rb = blockIdx.x * 64;
    #pragma unroll
    for (int i = 0; i < 8; i++) {
        int lin = t + i * 256;
        int row = lin >> 5;
        int c4 = lin & 31;
        float4 v = make_float4(0.f, 0.f, 0.f, 0.f);
        int gr = rb + row;
        if (gr < N_NODES) v = *(const float4*)&X[gr * 128 + c4 * 4];
        unsigned w0 = (unsigned)f2bf(v.x) | ((unsigned)f2bf(v.y) << 16);
        unsigned w1 = (unsigned)f2bf(v.z) | ((unsigned)f2bf(v.w) << 16);
        *(uint2*)&As[row][c4 * 4] = make_uint2(w0, w1);
    }
    int w = t >> 6, l = t & 63;
    int wr = (w >> 1) * 32, wc = (w & 1) * 32;
    int lr = l & 15, lk = (l >> 4) * 8;
    int drow = (l >> 4) * 4;
    int dcol = l & 15;
    for (int cb4 = 0; cb4 < 4; cb4++) {
        int cb = cb4 * 64;
        __syncthreads();
        #pragma unroll
        for (int i = 0; i < 4; i++) {
            int lin = t + i * 256;
            int n = lin >> 4;
            int k8 = lin & 15;
            *(uint4*)&Bs[n][k8 * 8] = *(const uint4*)&W1t[(cb + n) * 128 + k8 * 8];
        }
        __syncthreads();
        f32x4 c00 = {0.f,0.f,0.f,0.f}, c01 = {0.f,0.f,0.f,0.f};
        f32x4 c10 = {0.f,0.f,0.f,0.f}, c11 = {0.f,0.f,0.f,0.f};
        #pragma unroll
        for (int kk = 0; kk < 128; kk += 32) {
            short8 a0 = *(const short8*)&As[wr + lr][kk + lk];
            short8 a1 = *(const short8*)&As[wr + 16 + lr][kk + lk];
            short8 b0 = *(const short8*)&Bs[wc + lr][kk + lk];
            short8 b1 = *(const short8*)&Bs[wc + 16 + lr][kk + lk];
            c00 = __builtin_amdgcn_mfma_f32_16x16x32_bf16(a0, b0, c00, 0, 0, 0);
            c01 = __builtin_amdgcn_mfma_f32_16x16x32_bf16(a0, b1, c01, 0, 0, 0);
            c10 = __builtin_amdgcn_mfma_f32_16x16x32_bf16(a1, b0, c10, 0, 0, 0);
            c11 = __builtin_amdgcn_mfma_f32_16x16x32_bf16(a1, b1, c11, 0, 0, 0);
        }
        f32x4 cc[2][2] = {{c00, c01}, {c10, c11}};
        #pragma unroll
        for (int i = 0; i < 2; i++)
            #pragma unroll
            for (int j = 0; j < 2; j++)
                #pragma unroll
                for (int rg = 0; rg < 4; rg++) {
                    int gr = rb + wr + i * 16 + drow + rg;
                    int gc = cb + wc + j * 16 + dcol;
                    if (gr < N_NODES) hr_all[gr * 256 + gc] = f2bf(cc[i][j][rg]);
                }
    }
}

// ---------------- RGCN aggregate: 4 edges/wave (16 lanes/edge), unroll 16, pk-f32 accum ----------------
__global__ __launch_bounds__(256) void rgcn_kernel(const unsigned short* __restrict__ hr,
                                                   const float* __restrict__ brg, const int* __restrict__ rs,
                                                   const unsigned int* __restrict__ ep,
                                                   const float* __restrict__ epw,
                                                   unsigned short* __restrict__ Hm) {
    int t = threadIdx.x, lane = t & 63;
    int n = blockIdx.x * 4 + (t >> 6);
    if (n >= N_NODES) return;
    int slot = lane >> 4, pos = lane & 15;
    const uint2* H2 = (const uint2*)hr;
    f32x2 a01 = {0.f, 0.f}, a23 = {0.f, 0.f};
    int p0 = rs[n], p1 = rs[n + 1];
    for (int base = p0; base < p1; base += 64) {
        int pc = base + lane;
        unsigned chunk = (pc < p1) ? ep[pc] : 0u;
        float wch = (pc < p1) ? epw[pc] : 0.f;   // 0 beyond cnt -> free masking
        int cnt = min(64, p1 - base);
        int g0 = 0;
        for (; g0 + 16 <= cnt; g0 += 16) {
            int i0 = g0 + slot;
            int e0 = __shfl((int)chunk, i0);
            int e1 = __shfl((int)chunk, i0 + 4);
            int e2 = __shfl((int)chunk, i0 + 8);
            int e3 = __shfl((int)chunk, i0 + 12);
            float w0 = __shfl(wch, i0);
            float w1 = __shfl(wch, i0 + 4);
            float w2 = __shfl(wch, i0 + 8);
            float w3 = __shfl(wch, i0 + 12);
            uint2 h0 = H2[e0 * 16 + pos];
            uint2 h1 = H2[e1 * 16 + pos];
            uint2 h2v = H2[e2 * 16 + pos];
            uint2 h3 = H2[e3 * 16 + pos];
            a01 += w0 * bfpair(h0.x); a23 += w0 * bfpair(h0.y);
            a01 += w1 * bfpair(h1.x); a23 += w1 * bfpair(h1.y);
            a01 += w2 * bfpair(h2v.x); a23 += w2 * bfpair(h2v.y);
            a01 += w3 * bfpair(h3.x); a23 += w3 * bfpair(h3.y);
        }
        for (; g0 < cnt; g0 += 8) {
            int iA = g0 + slot, iB = iA + 4;
            int e0 = __shfl((int)chunk, iA);
            int e1 = __shfl((int)chunk, iB);
            float w0 = __shfl(wch, iA);
            float w1 = __shfl(wch, iB);
            uint2 h0 = H2[e0 * 16 + pos];
            uint2 h1 = H2[e1 * 16 + pos];
            a01 += w0 * bfpair(h0.x); a23 += w0 * bfpair(h0.y);
            a01 += w1 * bfpair(h1.x); a23 += w1 * bfpair(h1.y);
        }
    }
    a01.x += __shfl_xor(a01.x, 16); a01.x += __shfl_xor(a01.x, 32);
    a01.y += __shfl_xor(a01.y, 16); a01.y += __shfl_xor(a01.y, 32);
    a23.x += __shfl_xor(a23.x, 16); a23.x += __shfl_xor(a23.x, 32);
    a23.y += __shfl_xor(a23.y, 16); a23.y += __shfl_xor(a23.y, 32);
    uint2 rt = H2[(n * 4 + 3) * 16 + pos];   // root block
    f32x2 r01 = bfpair(rt.x), r23 = bfpair(rt.y);
    float4 bb = ((const float4*)brg)[pos];
    float h0 = fmaxf(r01.x + bb.x + a01.x, 0.f);
    float h1 = fmaxf(r01.y + bb.y + a01.y, 0.f);
    float h2s = fmaxf(r23.x + bb.z + a23.x, 0.f);
    float h3 = fmaxf(r23.y + bb.w + a23.y, 0.f);
    if (slot == 0) {
        uint2 wv;
        wv.x = (unsigned)f2bf(h0) | ((unsigned)f2bf(h1) << 16);
        wv.y = (unsigned)f2bf(h2s) | ((unsigned)f2bf(h3) << 16);
        ((uint2*)Hm)[n * 16 + pos] = wv;
    }
}

// ---------------- GEMM2 (MFMA bf16): Hm[N,64] @ W2[64,512] + bcat -> QS,KV (fp16 [N][256] each) ----------------
// QS row: [Q(128, pre-scaled by QSC) | skip(128)] ; KV row: [K(128) | V(128)]
__global__ __launch_bounds__(256) void gemm2_mfma(const unsigned short* __restrict__ Hm,
                                                  const unsigned short* __restrict__ W2t,
                                                  const float* __restrict__ bcat,
                                                  _Float16* __restrict__ QS, _Float16* __restrict__ KV) {
    __shared__ unsigned short As[64][72];
    __shared__ unsigned short Bs[64][72];
    int t = threadIdx.x;
    int rb = blockIdx.x * 64;
    #pragma unroll
    for (int i = 0; i < 2; i++) {
        int lin = t + i * 256;
        int row = lin >> 3;
        int k8 = lin & 7;
        uint4 v = make_uint4(0, 0, 0, 0);
        int gr = rb + row;
        if (gr < N_NODES) v = *(const uint4*)&Hm[gr * 64 + k8 * 8];
        *(uint4*)&As[row][k8 * 8] = v;
    }
    int w = t >> 6, l = t & 63;
    int wr = (w >> 1) * 32, wc = (w & 1) * 32;
    int lr = l & 15, lk = (l >> 4) * 8;
    int drow = (l >> 4) * 4;
    int dcol = l & 15;
    for (int cb8 = 0; cb8 < 8; cb8++) {
        int cb = cb8 * 64;
        float qsc = (cb8 < 2) ? QSC : 1.f;
        __syncthreads();
        #pragma unroll
        for (int i = 0; i < 2; i++) {
            int lin = t + i * 256;
            int n = lin >> 3;
            int k8 = lin & 7;
            *(uint4*)&Bs[n][k8 * 8] = *(const uint4*)&W2t[(cb + n) * 64 + k8 * 8];
        }
        __syncthreads();
        f32x4 c00 = {0.f,0.f,0.f,0.f}, c01 = {0.f,0.f,0.f,0.f};
        f32x4 c10 = {0.f,0.f,0.f,0.f}, c11 = {0.f,0.f,0.f,0.f};
        #pragma unroll
        for (int kk = 0; kk < 64; kk += 32) {
            short8 a0 = *(const short8*)&As[wr + lr][kk + lk];
            short8 a1 = *(const short8*)&As[wr + 16 + lr][kk + lk];
            short8 b0 = *(const short8*)&Bs[wc + lr][kk + lk];
            short8 b1 = *(const short8*)&Bs[wc + 16 + lr][kk + lk];
            c00 = __builtin_amdgcn_mfma_f32_16x16x32_bf16(a0, b0, c00, 0, 0, 0);
            c01 = __builtin_amdgcn_mfma_f32_16x16x32_bf16(a0, b1, c01, 0, 0, 0);
            c10 = __builtin_amdgcn_mfma_f32_16x16x32_bf16(a1, b0, c10, 0, 0, 0);
            c11 = __builtin_amdgcn_mfma_f32_16x16x32_bf16(a1, b1, c11, 0, 0, 0);
        }
        f32x4 cc[2][2] = {{c00, c01}, {c10, c11}};
        #pragma unroll
        for (int i = 0; i < 2; i++)
            #pragma unroll
            for (int j = 0; j < 2; j++)
                #pragma unroll
                for (int rg = 0; rg < 4; rg++) {
                    int gr = rb + wr + i * 16 + drow + rg;
                    int gc = cb + wc + j * 16 + dcol;
                    if (gr >= N_NODES) continue;
                    float v = (cc[i][j][rg] + bcat[gc]) * qsc;
                    _Float16 h = (_Float16)v;
                    if (gc < 128) QS[gr * 256 + gc] = h;
                    else if (gc < 384) KV[gr * 256 + gc - 128] = h;
                    else QS[gr * 256 + gc - 256] = h;
                }
    }
}

// ---------------- fused attention + skip + classifier: 4 edges/wave, 16 lanes/edge, fp16 packed ----------------
__global__ __launch_bounds__(256) void attn_kernel(const _Float16* __restrict__ QS,
                                                   const _Float16* __restrict__ KV,
                                                   const int* __restrict__ rs, const unsigned int* __restrict__ ep,
                                                   const float* __restrict__ Wf, const float* __restrict__ bfv,
                                                   float* __restrict__ out) {
    int t = threadIdx.x, lane = t & 63;
    int n = blockIdx.x * 4 + (t >> 6);
    if (n >= N_NODES) return;
    int slot = lane >> 4, pos = lane & 15;   // lane covers dims pos*8..pos*8+7 of edge-slot `slot`
    const uint4* KV4 = (const uint4*)KV;
    const uint4* QS4 = (const uint4*)QS;
    uint4 qv = QS4[n * 32 + pos];
    h2 qh[4] = { __builtin_bit_cast(h2, qv.x), __builtin_bit_cast(h2, qv.y),
                 __builtin_bit_cast(h2, qv.z), __builtin_bit_cast(h2, qv.w) };
    h2 o[4] = { h2{0,0}, h2{0,0}, h2{0,0}, h2{0,0} };
    float d = 0.f;
    int p0 = rs[n], p1 = rs[n + 1];
    for (int base = p0; base < p1; base += 64) {
        int pc = base + lane;
        unsigned chunk = (pc < p1) ? ep[pc] : 0u;
        int cnt = min(64, p1 - base);
        int g0 = 0;
        for (; g0 + 16 <= cnt; g0 += 16) {      // fully-valid groups: no masking
            int i0 = g0 + slot;
            int e0 = __shfl((int)chunk, i0);
            int e1 = __shfl((int)chunk, i0 + 4);
            int e2 = __shfl((int)chunk, i0 + 8);
            int e3 = __shfl((int)chunk, i0 + 12);
            int b0 = ((e0 >> 2) << 5) + pos;
            int b1 = ((e1 >> 2) << 5) + pos;
            int b2 = ((e2 >> 2) << 5) + pos;
            int b3 = ((e3 >> 2) << 5) + pos;
            uint4 k0 = KV4[b0], v0 = KV4[b0 + 16];
            uint4 k1 = KV4[b1], v1 = KV4[b1 + 16];
            uint4 k2 = KV4[b2], v2 = KV4[b2 + 16];
            uint4 k3 = KV4[b3], v3 = KV4[b3 + 16];
            float d0 = dot8h(qh, k0);
            float d1 = dot8h(qh, k1);
            float d2 = dot8h(qh, k2);
            float d3 = dot8h(qh, k3);
            d0 += __shfl_xor(d0, 1); d1 += __shfl_xor(d1, 1); d2 += __shfl_xor(d2, 1); d3 += __shfl_xor(d3, 1);
            d0 += __shfl_xor(d0, 2); d1 += __shfl_xor(d1, 2); d2 += __shfl_xor(d2, 2); d3 += __shfl_xor(d3, 2);
            float w0 = __builtin_amdgcn_exp2f(d0);
            float w1 = __builtin_amdgcn_exp2f(d1);
            float w2 = __builtin_amdgcn_exp2f(d2);
            float w3 = __builtin_amdgcn_exp2f(d3);
            d += (w0 + w1) + (w2 + w3);
            pv8h(o, w0, v0); pv8h(o, w1, v1); pv8h(o, w2, v2); pv8h(o, w3, v3);
        }
        for (; g0 < cnt; g0 += 8) {             // remainder: masked
            int iA = g0 + slot, iB = iA + 4;
            int e0 = __shfl((int)chunk, iA);
            int e1 = __shfl((int)chunk, iB);
            int b0 = ((e0 >> 2) << 5) + pos;
            int b1 = ((e1 >> 2) << 5) + pos;
            uint4 k0 = KV4[b0], v0 = KV4[b0 + 16];
            uint4 k1 = KV4[b1], v1 = KV4[b1 + 16];
            float d0 = dot8h(qh, k0);
            float d1 = dot8h(qh, k1);
            d0 += __shfl_xor(d0, 1); d1 += __shfl_xor(d1, 1);
            d0 += __shfl_xor(d0, 2); d1 += __shfl_xor(d1, 2);
            float w0 = (iA < cnt) ? __builtin_amdgcn_exp2f(d0) : 0.f;
            float w1 = (iB < cnt) ? __builtin_amdgcn_exp2f(d1) : 0.f;
            d += w0 + w1;
            pv8h(o, w0, v0); pv8h(o, w1, v1);
        }
    }
    // combine the 4 edge-slots
    float of[8];
    #pragma unroll
    for (int i = 0; i < 4; i++) { of[2 * i] = (float)o[i].x; of[2 * i + 1] = (float)o[i].y; }
    d += __shfl_xor(d, 16); d += __shfl_xor(d, 32);
    #pragma unroll
    for (int i = 0; i < 8; i++) { of[i] += __shfl_xor(of[i], 16); of[i] += __shfl_xor(of[i], 32); }
    float inv = (d > 0.f) ? 1.f / d : 0.f;
    uint4 sv = QS4[n * 32 + 16 + pos];
    h2 sh[4] = { __builtin_bit_cast(h2, sv.x), __builtin_bit_cast(h2, sv.y),
                 __builtin_bit_cast(h2, sv.z), __builtin_bit_cast(h2, sv.w) };
    float rf[8];
    #pragma unroll
    for (int i = 0; i < 4; i++) {
        rf[2 * i]     = fmaxf((float)sh[i].x + of[2 * i] * inv, 0.f);
        rf[2 * i + 1] = fmaxf((float)sh[i].y + of[2 * i + 1] * inv, 0.f);
    }
    // classifier: slot s handles dims pos*8 + s*2 + {0,1}
    float rr0 = (slot == 0) ? rf[0] : (slot == 1) ? rf[2] : (slot == 2) ? rf[4] : rf[6];
    float rr1 = (slot == 0) ? rf[1] : (slot == 1) ? rf[3] : (slot == 2) ? rf[5] : rf[7];
    int gd = pos * 8 + slot * 2;
    float acc[7];
    #pragma unroll
    for (int j = 0; j < 7; j++) acc[j] = rr0 * Wf[gd * 7 + j] + rr1 * Wf[gd * 7 + 7 + j];
    #pragma unroll
    for (int j = 0; j < 7; j++) {
        acc[j] += __shfl_xor(acc[j], 1);
        acc[j] += __shfl_xor(acc[j], 2);
        acc[j] += __shfl_xor(acc[j], 4);
        acc[j] += __shfl_xor(acc[j], 8);
        acc[j] += __shfl_xor(acc[j], 16);
        acc[j] += __shfl_xor(acc[j], 32);
    }
    if (lane == 0) {
        #pragma unroll
        for (int j = 0; j < 7; j++) out[n * 7 + j] = acc[j] + bfv[j];
    }
}

extern "C" void kernel_launch(void* const* d_in, const int* in_sizes, int n_in,
                              void* d_out, int out_size, void* d_ws, size_t ws_size,
                              hipStream_t stream) {
    const float* x     = (const float*)d_in[0];
    const int*   ei    = (const int*)d_in[2];
    const int*   et    = (const int*)d_in[3];
    const float* Wrel  = (const float*)d_in[4];
    const float* Wroot = (const float*)d_in[5];
    const float* brg   = (const float*)d_in[6];
    const float* Wq    = (const float*)d_in[7];
    const float* bq    = (const float*)d_in[8];
    const float* Wk    = (const float*)d_in[9];
    const float* bk    = (const float*)d_in[10];
    const float* Wv    = (const float*)d_in[11];
    const float* bv    = (const float*)d_in[12];
    const float* Wsk   = (const float*)d_in[13];
    const float* bsk   = (const float*)d_in[14];
    const float* Wf    = (const float*)d_in[15];
    const float* bfv   = (const float*)d_in[16];
    float* out = (float*)d_out;

    // workspace layout (~130.2 MB):
    //  [0,       51.2M)  hr_all bf16 [N][256] (dead after rgcn); then QS fp16 [N][256] overlay
    //  [51.2M,  102.4M)  KV fp16 [N][256]  ([K|V] interleaved)
    //  [102.4M, 115.2M)  Hm bf16 [N,64]
    //  [115.2M, 121.6M)  ep u32 [E]  (src*4+r)
    //  [121.6M, 128.0M)  epw f32 [E] (1/cnt_r(dst))
    //  then rs / cntr+fill (contiguous memset) / part / W1t / W2t / bcat
    char* ws = (char*)d_ws;
    unsigned short* hr_all = (unsigned short*)(ws + 0);
    _Float16*       QS     = (_Float16*)(ws + 0);
    _Float16*       KV     = (_Float16*)(ws + 51200000);
    unsigned short* Hm     = (unsigned short*)(ws + 102400000);
    unsigned int*   ep     = (unsigned int*)(ws + 115200000);
    float*          epw    = (float*)(ws + 121600000);
    int*            rs     = (int*)(ws + 128000000);
    int*            cntr   = (int*)(ws + 128400016);
    int*            fill   = (int*)(ws + 129600016);
    int*            part   = (int*)(ws + 130000016);
    unsigned short* W1t    = (unsigned short*)(ws + 130000528);
    unsigned short* W2t    = (unsigned short*)(ws + 130066064);
    float*          bcat   = (float*)(ws + 130131600);

    hipMemsetAsync(cntr, 0, 4 * N_NODES * sizeof(int), stream);   // cntr (3N) + fill (N) contiguous

    repack_kernel<<<258, 256, 0, stream>>>(Wrel, Wroot, Wq, Wk, Wv, Wsk, bq, bk, bv, bsk, W1t, W2t, bcat);

    // CSR build by destination
    hist_kernel<<<N_EDGES / 256, 256, 0, stream>>>(ei, et, cntr);
    scanA_kernel<<<98, 256, 0, stream>>>(cntr, part);
    scanC_kernel<<<98, 256, 0, stream>>>(cntr, part, rs);
    scatter_kernel<<<N_EDGES / 256, 256, 0, stream>>>(ei, et, rs, cntr, fill, ep, epw);

    // RGCN
    gemm1_mfma<<<1563, 256, 0, stream>>>(x, W1t, hr_all);
    rgcn_kernel<<<25000, 256, 0, stream>>>(hr_all, brg, rs, ep, epw, Hm);

    // TransformerConv
    gemm2_mfma<<<1563, 256, 0, stream>>>(Hm, W2t, bcat, QS, KV);
    attn_kernel<<<25000, 256, 0, stream>>>(QS, KV, rs, ep, Wf, bfv, out);
}

// Round 7
// 440.142 us; speedup vs baseline: 1.9886x; 1.1462x over previous
//
#include <hip/hip_runtime.h>
#include <math.h>

#define N_NODES 100000
#define N_EDGES 1600000

typedef short short8 __attribute__((ext_vector_type(8)));
typedef float f32x4 __attribute__((ext_vector_type(4)));
typedef float f32x2 __attribute__((ext_vector_type(2)));
typedef _Float16 h2 __attribute__((ext_vector_type(2)));

// 1/sqrt(32) * log2(e)  (fold softmax scale + exp2 conversion into Q)
#define QSC 0.25503540f

static __device__ __forceinline__ float bf2f(unsigned int u16) {
    return __uint_as_float(u16 << 16);
}
static __device__ __forceinline__ unsigned short f2bf(float f) {
    unsigned u = __float_as_uint(f);
    unsigned r = u + 0x7FFF + ((u >> 16) & 1);   // RTNE
    return (unsigned short)(r >> 16);
}
static __device__ __forceinline__ f32x2 bfpair(unsigned u) {
    f32x2 r;
    r.x = __uint_as_float(u << 16);
    r.y = __uint_as_float(u & 0xFFFF0000u);
    return r;
}
static __device__ __forceinline__ float dot8h(const h2* q, uint4 k) {
    h2 s = q[0] * __builtin_bit_cast(h2, k.x);
    s += q[1] * __builtin_bit_cast(h2, k.y);
    s += q[2] * __builtin_bit_cast(h2, k.z);
    s += q[3] * __builtin_bit_cast(h2, k.w);
    return (float)s.x + (float)s.y;
}
static __device__ __forceinline__ void pv8h(h2* o, float w, uint4 v) {
    _Float16 wh = (_Float16)w;
    o[0] += wh * __builtin_bit_cast(h2, v.x);
    o[1] += wh * __builtin_bit_cast(h2, v.y);
    o[2] += wh * __builtin_bit_cast(h2, v.z);
    o[3] += wh * __builtin_bit_cast(h2, v.w);
}

// ---------------- weight repack ----------------
__global__ void repack_kernel(const float* __restrict__ Wrel, const float* __restrict__ Wroot,
                              const float* __restrict__ Wq, const float* __restrict__ Wk,
                              const float* __restrict__ Wv, const float* __restrict__ Wsk,
                              const float* __restrict__ bq, const float* __restrict__ bk,
                              const float* __restrict__ bv, const float* __restrict__ bsk,
                              unsigned short* __restrict__ W1t, unsigned short* __restrict__ W2t,
                              float* __restrict__ bcat) {
    int idx = blockIdx.x * 256 + threadIdx.x;
    if (idx < 128 * 256) {
        int k = idx >> 8, c = idx & 255;
        float v;
        if (c < 192) { int r = c >> 6, cc = c & 63; v = Wrel[r * 8192 + k * 64 + cc]; }
        else v = Wroot[k * 64 + (c - 192)];
        W1t[c * 128 + k] = f2bf(v);
    }
    int i2 = idx - 128 * 256;
    if (i2 >= 0 && i2 < 64 * 512) {
        int k = i2 >> 9, c = i2 & 511;
        float v;
        if (c < 128) v = Wq[k * 128 + c];
        else if (c < 256) v = Wk[k * 128 + c - 128];
        else if (c < 384) v = Wv[k * 128 + c - 256];
        else v = Wsk[k * 128 + c - 384];
        W2t[c * 64 + k] = f2bf(v);
    }
    int i3 = idx - 128 * 256 - 64 * 512;
    if (i3 >= 0 && i3 < 512) {
        float v;
        if (i3 < 128) v = bq[i3];
        else if (i3 < 256) v = bk[i3 - 128];
        else if (i3 < 384) v = bv[i3 - 256];
        else v = bsk[i3 - 384];
        bcat[i3] = v;
    }
}

// ---------------- CSR build ----------------
// hist: per-(relation,dst) counts + per-edge rank within its (r,dst) group
__global__ void hist_kernel(const int* __restrict__ ei, const int* __restrict__ et,
                            int* __restrict__ cntr, int* __restrict__ rank) {
    int e = blockIdx.x * 256 + threadIdx.x;
    if (e < N_EDGES) rank[e] = atomicAdd(&cntr[et[e] * N_NODES + ei[N_EDGES + e]], 1);
}

__global__ void scanA_kernel(const int* __restrict__ cntr, int* __restrict__ part) {
    __shared__ int wsum[4];
    int t = threadIdx.x;
    int base = blockIdx.x * 1024 + t * 4;
    int s = 0;
    for (int i = 0; i < 4; i++) {
        int idx = base + i;
        if (idx < N_NODES) s += cntr[idx] + cntr[N_NODES + idx] + cntr[2 * N_NODES + idx];
    }
    for (int off = 1; off < 64; off <<= 1) s += __shfl_xor(s, off);
    if ((t & 63) == 0) wsum[t >> 6] = s;
    __syncthreads();
    if (t == 0) part[blockIdx.x] = wsum[0] + wsum[1] + wsum[2] + wsum[3];
}

// scanC: bro[n] = {rs, rs+c0, rs+c0+c1, rs+c0+c1+c2}
__global__ void scanC_kernel(const int* __restrict__ cntr, const int* __restrict__ part,
                             uint4* __restrict__ bro) {
    __shared__ int wsum[4];
    __shared__ int ws2[4];
    int t = threadIdx.x;
    int lane = t & 63;
    int base = blockIdx.x * 1024 + t * 4;
    int c0v[4], c1v[4], c2v[4]; int tsum = 0;
    for (int i = 0; i < 4; i++) {
        int idx = base + i;
        if (idx < N_NODES) {
            c0v[i] = cntr[idx]; c1v[i] = cntr[N_NODES + idx]; c2v[i] = cntr[2 * N_NODES + idx];
        } else { c0v[i] = c1v[i] = c2v[i] = 0; }
        tsum += c0v[i] + c1v[i] + c2v[i];
    }
    int p = (t < blockIdx.x) ? part[t] : 0;
    for (int off = 1; off < 64; off <<= 1) p += __shfl_xor(p, off);
    if (lane == 0) ws2[t >> 6] = p;
    int x = tsum;
    for (int off = 1; off < 64; off <<= 1) { int y = __shfl_up(x, off); if (lane >= off) x += y; }
    if (lane == 63) wsum[t >> 6] = x;
    __syncthreads();
    if (t == 0) { int run = 0; for (int w = 0; w < 4; w++) { int tmp = wsum[w]; wsum[w] = run; run += tmp; } }
    __syncthreads();
    int bofs = ws2[0] + ws2[1] + ws2[2] + ws2[3];
    int excl = x - tsum + wsum[t >> 6] + bofs;
    for (int i = 0; i < 4; i++) {
        int idx = base + i;
        if (idx < N_NODES) {
            uint4 b;
            b.x = (unsigned)excl;
            b.y = (unsigned)(excl + c0v[i]);
            b.z = (unsigned)(excl + c0v[i] + c1v[i]);
            b.w = (unsigned)(excl + c0v[i] + c1v[i] + c2v[i]);
            bro[idx] = b;
        }
        excl += c0v[i] + c1v[i] + c2v[i];
    }
}

// scatter: no atomics — pos = bro[dst].sel(r) + rank[e]
__global__ void scatter_kernel(const int* __restrict__ ei, const int* __restrict__ et,
                               const uint4* __restrict__ bro, const int* __restrict__ rank,
                               unsigned int* __restrict__ ep) {
    int e = blockIdx.x * 256 + threadIdx.x;
    if (e >= N_EDGES) return;
    int src = ei[e], dst = ei[N_EDGES + e], r = et[e], rk = rank[e];
    uint4 b = bro[dst];
    unsigned ofs = (r == 0) ? b.x : (r == 1) ? b.y : b.z;
    ep[ofs + rk] = ((unsigned)src << 2) | (unsigned)r;
}

// ---------------- GEMM1 (MFMA bf16): X[N,128] @ W1[128,256] -> hr_all bf16 [N][256] ----------------
__global__ __launch_bounds__(256) void gemm1_mfma(const float* __restrict__ X,
                                                  const unsigned short* __restrict__ W1t,
                                                  unsigned short* __restrict__ hr_all) {
    __shared__ unsigned short As[64][136];
    __shared__ unsigned short Bs[64][136];
    int t = threadIdx.x;
    int rb = blockIdx.x * 64;
    #pragma unroll
    for (int i = 0; i < 8; i++) {
        int lin = t + i * 256;
        int row = lin >> 5;
        int c4 = lin & 31;
        float4 v = make_float4(0.f, 0.f, 0.f, 0.f);
        int gr = rb + row;
        if (gr < N_NODES) v = *(const float4*)&X[gr * 128 + c4 * 4];
        unsigned w0 = (unsigned)f2bf(v.x) | ((unsigned)f2bf(v.y) << 16);
        unsigned w1 = (unsigned)f2bf(v.z) | ((unsigned)f2bf(v.w) << 16);
        *(uint2*)&As[row][c4 * 4] = make_uint2(w0, w1);
    }
    int w = t >> 6, l = t & 63;
    int wr = (w >> 1) * 32, wc = (w & 1) * 32;
    int lr = l & 15, lk = (l >> 4) * 8;
    int drow = (l >> 4) * 4;
    int dcol = l & 15;
    for (int cb4 = 0; cb4 < 4; cb4++) {
        int cb = cb4 * 64;
        __syncthreads();
        #pragma unroll
        for (int i = 0; i < 4; i++) {
            int lin = t + i * 256;
            int n = lin >> 4;
            int k8 = lin & 15;
            *(uint4*)&Bs[n][k8 * 8] = *(const uint4*)&W1t[(cb + n) * 128 + k8 * 8];
        }
        __syncthreads();
        f32x4 c00 = {0.f,0.f,0.f,0.f}, c01 = {0.f,0.f,0.f,0.f};
        f32x4 c10 = {0.f,0.f,0.f,0.f}, c11 = {0.f,0.f,0.f,0.f};
        #pragma unroll
        for (int kk = 0; kk < 128; kk += 32) {
            short8 a0 = *(const short8*)&As[wr + lr][kk + lk];
            short8 a1 = *(const short8*)&As[wr + 16 + lr][kk + lk];
            short8 b0 = *(const short8*)&Bs[wc + lr][kk + lk];
            short8 b1 = *(const short8*)&Bs[wc + 16 + lr][kk + lk];
            c00 = __builtin_amdgcn_mfma_f32_16x16x32_bf16(a0, b0, c00, 0, 0, 0);
            c01 = __builtin_amdgcn_mfma_f32_16x16x32_bf16(a0, b1, c01, 0, 0, 0);
            c10 = __builtin_amdgcn_mfma_f32_16x16x32_bf16(a1, b0, c10, 0, 0, 0);
            c11 = __builtin_amdgcn_mfma_f32_16x16x32_bf16(a1, b1, c11, 0, 0, 0);
        }
        f32x4 cc[2][2] = {{c00, c01}, {c10, c11}};
        #pragma unroll
        for (int i = 0; i < 2; i++)
            #pragma unroll
            for (int j = 0; j < 2; j++)
                #pragma unroll
                for (int rg = 0; rg < 4; rg++) {
                    int gr = rb + wr + i * 16 + drow + rg;
                    int gc = cb + wc + j * 16 + dcol;
                    if (gr < N_NODES) hr_all[gr * 256 + gc] = f2bf(cc[i][j][rg]);
                }
    }
}

// ---------------- RGCN aggregate: 4 edges/wave (16 lanes/edge), unroll 16, weights from bro ----------------
__global__ __launch_bounds__(256) void rgcn_kernel(const unsigned short* __restrict__ hr,
                                                   const float* __restrict__ brg,
                                                   const uint4* __restrict__ bro,
                                                   const unsigned int* __restrict__ ep,
                                                   unsigned short* __restrict__ Hm) {
    int t = threadIdx.x, lane = t & 63;
    int n = blockIdx.x * 4 + (t >> 6);
    if (n >= N_NODES) return;
    int slot = lane >> 4, pos = lane & 15;
    const uint2* H2 = (const uint2*)hr;
    uint4 b = bro[n];
    int p0 = (int)b.x, p1 = (int)b.w;
    int c0 = (int)(b.y - b.x), c1 = (int)(b.z - b.y), c2 = (int)(b.w - b.z);
    float i0 = c0 ? 1.f / (float)c0 : 0.f;
    float i1 = c1 ? 1.f / (float)c1 : 0.f;
    float i2 = c2 ? 1.f / (float)c2 : 0.f;
    f32x2 a01 = {0.f, 0.f}, a23 = {0.f, 0.f};
    for (int base = p0; base < p1; base += 64) {
        int pc = base + lane;
        unsigned chunk = (pc < p1) ? ep[pc] : 0u;
        int cnt = min(64, p1 - base);
        int g0 = 0;
        for (; g0 + 16 <= cnt; g0 += 16) {       // fully valid
            int i0x = g0 + slot;
            int e0 = __shfl((int)chunk, i0x);
            int e1 = __shfl((int)chunk, i0x + 4);
            int e2 = __shfl((int)chunk, i0x + 8);
            int e3 = __shfl((int)chunk, i0x + 12);
            float w0 = ((e0 & 3) == 0) ? i0 : ((e0 & 3) == 1) ? i1 : i2;
            float w1 = ((e1 & 3) == 0) ? i0 : ((e1 & 3) == 1) ? i1 : i2;
            float w2 = ((e2 & 3) == 0) ? i0 : ((e2 & 3) == 1) ? i1 : i2;
            float w3 = ((e3 & 3) == 0) ? i0 : ((e3 & 3) == 1) ? i1 : i2;
            uint2 h0 = H2[(unsigned)e0 * 16 + pos];
            uint2 h1 = H2[(unsigned)e1 * 16 + pos];
            uint2 h2v = H2[(unsigned)e2 * 16 + pos];
            uint2 h3 = H2[(unsigned)e3 * 16 + pos];
            a01 += w0 * bfpair(h0.x); a23 += w0 * bfpair(h0.y);
            a01 += w1 * bfpair(h1.x); a23 += w1 * bfpair(h1.y);
            a01 += w2 * bfpair(h2v.x); a23 += w2 * bfpair(h2v.y);
            a01 += w3 * bfpair(h3.x); a23 += w3 * bfpair(h3.y);
        }
        for (; g0 < cnt; g0 += 8) {              // remainder: explicit masking
            int iA = g0 + slot, iB = iA + 4;
            int e0 = __shfl((int)chunk, iA);
            int e1 = __shfl((int)chunk, iB);
            float w0 = ((e0 & 3) == 0) ? i0 : ((e0 & 3) == 1) ? i1 : i2;
            float w1 = ((e1 & 3) == 0) ? i0 : ((e1 & 3) == 1) ? i1 : i2;
            w0 = (iA < cnt) ? w0 : 0.f;
            w1 = (iB < cnt) ? w1 : 0.f;
            uint2 h0 = H2[(unsigned)e0 * 16 + pos];
            uint2 h1 = H2[(unsigned)e1 * 16 + pos];
            a01 += w0 * bfpair(h0.x); a23 += w0 * bfpair(h0.y);
            a01 += w1 * bfpair(h1.x); a23 += w1 * bfpair(h1.y);
        }
    }
    a01.x += __shfl_xor(a01.x, 16); a01.x += __shfl_xor(a01.x, 32);
    a01.y += __shfl_xor(a01.y, 16); a01.y += __shfl_xor(a01.y, 32);
    a23.x += __shfl_xor(a23.x, 16); a23.x += __shfl_xor(a23.x, 32);
    a23.y += __shfl_xor(a23.y, 16); a23.y += __shfl_xor(a23.y, 32);
    uint2 rt = H2[(n * 4 + 3) * 16 + pos];   // root block
    f32x2 r01 = bfpair(rt.x), r23 = bfpair(rt.y);
    float4 bb = ((const float4*)brg)[pos];
    float h0 = fmaxf(r01.x + bb.x + a01.x, 0.f);
    float h1 = fmaxf(r01.y + bb.y + a01.y, 0.f);
    float h2s = fmaxf(r23.x + bb.z + a23.x, 0.f);
    float h3 = fmaxf(r23.y + bb.w + a23.y, 0.f);
    if (slot == 0) {
        uint2 wv;
        wv.x = (unsigned)f2bf(h0) | ((unsigned)f2bf(h1) << 16);
        wv.y = (unsigned)f2bf(h2s) | ((unsigned)f2bf(h3) << 16);
        ((uint2*)Hm)[n * 16 + pos] = wv;
    }
}

// ---------------- GEMM2 (MFMA bf16): Hm[N,64] @ W2[64,512] + bcat -> QS,KV (fp16 [N][256] each) ----------------
// QS row: [Q(128, pre-scaled by QSC) | skip(128)] ; KV row: [K(128) | V(128)]
__global__ __launch_bounds__(256) void gemm2_mfma(const unsigned short* __restrict__ Hm,
                                                  const unsigned short* __restrict__ W2t,
                                                  const float* __restrict__ bcat,
                                                  _Float16* __restrict__ QS, _Float16* __restrict__ KV) {
    __shared__ unsigned short As[64][72];
    __shared__ unsigned short Bs[64][72];
    int t = threadIdx.x;
    int rb = blockIdx.x * 64;
    #pragma unroll
    for (int i = 0; i < 2; i++) {
        int lin = t + i * 256;
        int row = lin >> 3;
        int k8 = lin & 7;
        uint4 v = make_uint4(0, 0, 0, 0);
        int gr = rb + row;
        if (gr < N_NODES) v = *(const uint4*)&Hm[gr * 64 + k8 * 8];
        *(uint4*)&As[row][k8 * 8] = v;
    }
    int w = t >> 6, l = t & 63;
    int wr = (w >> 1) * 32, wc = (w & 1) * 32;
    int lr = l & 15, lk = (l >> 4) * 8;
    int drow = (l >> 4) * 4;
    int dcol = l & 15;
    for (int cb8 = 0; cb8 < 8; cb8++) {
        int cb = cb8 * 64;
        float qsc = (cb8 < 2) ? QSC : 1.f;
        __syncthreads();
        #pragma unroll
        for (int i = 0; i < 2; i++) {
            int lin = t + i * 256;
            int n = lin >> 3;
            int k8 = lin & 7;
            *(uint4*)&Bs[n][k8 * 8] = *(const uint4*)&W2t[(cb + n) * 64 + k8 * 8];
        }
        __syncthreads();
        f32x4 c00 = {0.f,0.f,0.f,0.f}, c01 = {0.f,0.f,0.f,0.f};
        f32x4 c10 = {0.f,0.f,0.f,0.f}, c11 = {0.f,0.f,0.f,0.f};
        #pragma unroll
        for (int kk = 0; kk < 64; kk += 32) {
            short8 a0 = *(const short8*)&As[wr + lr][kk + lk];
            short8 a1 = *(const short8*)&As[wr + 16 + lr][kk + lk];
            short8 b0 = *(const short8*)&Bs[wc + lr][kk + lk];
            short8 b1 = *(const short8*)&Bs[wc + 16 + lr][kk + lk];
            c00 = __builtin_amdgcn_mfma_f32_16x16x32_bf16(a0, b0, c00, 0, 0, 0);
            c01 = __builtin_amdgcn_mfma_f32_16x16x32_bf16(a0, b1, c01, 0, 0, 0);
            c10 = __builtin_amdgcn_mfma_f32_16x16x32_bf16(a1, b0, c10, 0, 0, 0);
            c11 = __builtin_amdgcn_mfma_f32_16x16x32_bf16(a1, b1, c11, 0, 0, 0);
        }
        f32x4 cc[2][2] = {{c00, c01}, {c10, c11}};
        #pragma unroll
        for (int i = 0; i < 2; i++)
            #pragma unroll
            for (int j = 0; j < 2; j++)
                #pragma unroll
                for (int rg = 0; rg < 4; rg++) {
                    int gr = rb + wr + i * 16 + drow + rg;
                    int gc = cb + wc + j * 16 + dcol;
                    if (gr >= N_NODES) continue;
                    float v = (cc[i][j][rg] + bcat[gc]) * qsc;
                    _Float16 h = (_Float16)v;
                    if (gc < 128) QS[gr * 256 + gc] = h;
                    else if (gc < 384) KV[gr * 256 + gc - 128] = h;
                    else QS[gr * 256 + gc - 256] = h;
                }
    }
}

// ---------------- fused attention + skip + classifier: 4 edges/wave, 16 lanes/edge, fp16 packed ----------------
__global__ __launch_bounds__(256) void attn_kernel(const _Float16* __restrict__ QS,
                                                   const _Float16* __restrict__ KV,
                                                   const uint4* __restrict__ bro,
                                                   const unsigned int* __restrict__ ep,
                                                   const float* __restrict__ Wf, const float* __restrict__ bfv,
                                                   float* __restrict__ out) {
    int t = threadIdx.x, lane = t & 63;
    int n = blockIdx.x * 4 + (t >> 6);
    if (n >= N_NODES) return;
    int slot = lane >> 4, pos = lane & 15;   // lane covers dims pos*8..pos*8+7 of edge-slot `slot`
    const uint4* KV4 = (const uint4*)KV;
    const uint4* QS4 = (const uint4*)QS;
    uint4 qv = QS4[n * 32 + pos];
    h2 qh[4] = { __builtin_bit_cast(h2, qv.x), __builtin_bit_cast(h2, qv.y),
                 __builtin_bit_cast(h2, qv.z), __builtin_bit_cast(h2, qv.w) };
    h2 o[4] = { h2{0,0}, h2{0,0}, h2{0,0}, h2{0,0} };
    float d = 0.f;
    uint4 bnd = bro[n];
    int p0 = (int)bnd.x, p1 = (int)bnd.w;
    for (int base = p0; base < p1; base += 64) {
        int pc = base + lane;
        unsigned chunk = (pc < p1) ? ep[pc] : 0u;
        int cnt = min(64, p1 - base);
        int g0 = 0;
        for (; g0 + 16 <= cnt; g0 += 16) {      // fully-valid groups: no masking
            int i0 = g0 + slot;
            int e0 = __shfl((int)chunk, i0);
            int e1 = __shfl((int)chunk, i0 + 4);
            int e2 = __shfl((int)chunk, i0 + 8);
            int e3 = __shfl((int)chunk, i0 + 12);
            int b0 = ((e0 >> 2) << 5) + pos;
            int b1 = ((e1 >> 2) << 5) + pos;
            int b2 = ((e2 >> 2) << 5) + pos;
            int b3 = ((e3 >> 2) << 5) + pos;
            uint4 k0 = KV4[b0], v0 = KV4[b0 + 16];
            uint4 k1 = KV4[b1], v1 = KV4[b1 + 16];
            uint4 k2 = KV4[b2], v2 = KV4[b2 + 16];
            uint4 k3 = KV4[b3], v3 = KV4[b3 + 16];
            float d0 = dot8h(qh, k0);
            float d1 = dot8h(qh, k1);
            float d2 = dot8h(qh, k2);
            float d3 = dot8h(qh, k3);
            d0 += __shfl_xor(d0, 1); d1 += __shfl_xor(d1, 1); d2 += __shfl_xor(d2, 1); d3 += __shfl_xor(d3, 1);
            d0 += __shfl_xor(d0, 2); d1 += __shfl_xor(d1, 2); d2 += __shfl_xor(d2, 2); d3 += __shfl_xor(d3, 2);
            float w0 = __builtin_amdgcn_exp2f(d0);
            float w1 = __builtin_amdgcn_exp2f(d1);
            float w2 = __builtin_amdgcn_exp2f(d2);
            float w3 = __builtin_amdgcn_exp2f(d3);
            d += (w0 + w1) + (w2 + w3);
            pv8h(o, w0, v0); pv8h(o, w1, v1); pv8h(o, w2, v2); pv8h(o, w3, v3);
        }
        for (; g0 < cnt; g0 += 8) {             // remainder: masked
            int iA = g0 + slot, iB = iA + 4;
            int e0 = __shfl((int)chunk, iA);
            int e1 = __shfl((int)chunk, iB);
            int b0 = ((e0 >> 2) << 5) + pos;
            int b1 = ((e1 >> 2) << 5) + pos;
            uint4 k0 = KV4[b0], v0 = KV4[b0 + 16];
            uint4 k1 = KV4[b1], v1 = KV4[b1 + 16];
            float d0 = dot8h(qh, k0);
            float d1 = dot8h(qh, k1);
            d0 += __shfl_xor(d0, 1); d1 += __shfl_xor(d1, 1);
            d0 += __shfl_xor(d0, 2); d1 += __shfl_xor(d1, 2);
            float w0 = (iA < cnt) ? __builtin_amdgcn_exp2f(d0) : 0.f;
            float w1 = (iB < cnt) ? __builtin_amdgcn_exp2f(d1) : 0.f;
            d += w0 + w1;
            pv8h(o, w0, v0); pv8h(o, w1, v1);
        }
    }
    // combine the 4 edge-slots
    float of[8];
    #pragma unroll
    for (int i = 0; i < 4; i++) { of[2 * i] = (float)o[i].x; of[2 * i + 1] = (float)o[i].y; }
    d += __shfl_xor(d, 16); d += __shfl_xor(d, 32);
    #pragma unroll
    for (int i = 0; i < 8; i++) { of[i] += __shfl_xor(of[i], 16); of[i] += __shfl_xor(of[i], 32); }
    float inv = (d > 0.f) ? 1.f / d : 0.f;
    uint4 sv = QS4[n * 32 + 16 + pos];
    h2 sh[4] = { __builtin_bit_cast(h2, sv.x), __builtin_bit_cast(h2, sv.y),
                 __builtin_bit_cast(h2, sv.z), __builtin_bit_cast(h2, sv.w) };
    float rf[8];
    #pragma unroll
    for (int i = 0; i < 4; i++) {
        rf[2 * i]     = fmaxf((float)sh[i].x + of[2 * i] * inv, 0.f);
        rf[2 * i + 1] = fmaxf((float)sh[i].y + of[2 * i + 1] * inv, 0.f);
    }
    // classifier: slot s handles dims pos*8 + s*2 + {0,1}
    float rr0 = (slot == 0) ? rf[0] : (slot == 1) ? rf[2] : (slot == 2) ? rf[4] : rf[6];
    float rr1 = (slot == 0) ? rf[1] : (slot == 1) ? rf[3] : (slot == 2) ? rf[5] : rf[7];
    int gd = pos * 8 + slot * 2;
    float acc[7];
    #pragma unroll
    for (int j = 0; j < 7; j++) acc[j] = rr0 * Wf[gd * 7 + j] + rr1 * Wf[gd * 7 + 7 + j];
    #pragma unroll
    for (int j = 0; j < 7; j++) {
        acc[j] += __shfl_xor(acc[j], 1);
        acc[j] += __shfl_xor(acc[j], 2);
        acc[j] += __shfl_xor(acc[j], 4);
        acc[j] += __shfl_xor(acc[j], 8);
        acc[j] += __shfl_xor(acc[j], 16);
        acc[j] += __shfl_xor(acc[j], 32);
    }
    if (lane == 0) {
        #pragma unroll
        for (int j = 0; j < 7; j++) out[n * 7 + j] = acc[j] + bfv[j];
    }
}

extern "C" void kernel_launch(void* const* d_in, const int* in_sizes, int n_in,
                              void* d_out, int out_size, void* d_ws, size_t ws_size,
                              hipStream_t stream) {
    const float* x     = (const float*)d_in[0];
    const int*   ei    = (const int*)d_in[2];
    const int*   et    = (const int*)d_in[3];
    const float* Wrel  = (const float*)d_in[4];
    const float* Wroot = (const float*)d_in[5];
    const float* brg   = (const float*)d_in[6];
    const float* Wq    = (const float*)d_in[7];
    const float* bq    = (const float*)d_in[8];
    const float* Wk    = (const float*)d_in[9];
    const float* bk    = (const float*)d_in[10];
    const float* Wv    = (const float*)d_in[11];
    const float* bv    = (const float*)d_in[12];
    const float* Wsk   = (const float*)d_in[13];
    const float* bsk   = (const float*)d_in[14];
    const float* Wf    = (const float*)d_in[15];
    const float* bfv   = (const float*)d_in[16];
    float* out = (float*)d_out;

    // workspace layout (~131 MB):
    //  [0,       51.2M)  hr_all bf16 [N][256] (dead after rgcn); then QS fp16 [N][256] overlay
    //  [51.2M,  102.4M)  KV fp16 [N][256]  ([K|V] interleaved)
    //  [102.4M, 115.2M)  Hm bf16 [N,64]
    //  [115.2M, 121.6M)  ep u32 [E]  (src*4+r)
    //  [121.6M, 128.0M)  rank u32 [E]
    //  [128.0M, 129.6M)  bro uint4 [N]
    //  then cntr (memset) / part / W1t / W2t / bcat
    char* ws = (char*)d_ws;
    unsigned short* hr_all = (unsigned short*)(ws + 0);
    _Float16*       QS     = (_Float16*)(ws + 0);
    _Float16*       KV     = (_Float16*)(ws + 51200000);
    unsigned short* Hm     = (unsigned short*)(ws + 102400000);
    unsigned int*   ep     = (unsigned int*)(ws + 115200000);
    int*            rank   = (int*)(ws + 121600000);
    uint4*          bro    = (uint4*)(ws + 128000000);
    int*            cntr   = (int*)(ws + 129600016);
    int*            part   = (int*)(ws + 130800016);
    unsigned short* W1t    = (unsigned short*)(ws + 130800528);
    unsigned short* W2t    = (unsigned short*)(ws + 130866064);
    float*          bcat   = (float*)(ws + 130931600);

    hipMemsetAsync(cntr, 0, 3 * N_NODES * sizeof(int), stream);

    repack_kernel<<<258, 256, 0, stream>>>(Wrel, Wroot, Wq, Wk, Wv, Wsk, bq, bk, bv, bsk, W1t, W2t, bcat);

    // CSR build by destination (rank computed in hist; scatter has no atomics)
    hist_kernel<<<N_EDGES / 256, 256, 0, stream>>>(ei, et, cntr, rank);
    scanA_kernel<<<98, 256, 0, stream>>>(cntr, part);
    scanC_kernel<<<98, 256, 0, stream>>>(cntr, part, bro);
    scatter_kernel<<<N_EDGES / 256, 256, 0, stream>>>(ei, et, bro, rank, ep);

    // RGCN
    gemm1_mfma<<<1563, 256, 0, stream>>>(x, W1t, hr_all);
    rgcn_kernel<<<25000, 256, 0, stream>>>(hr_all, brg, bro, ep, Hm);

    // TransformerConv
    gemm2_mfma<<<1563, 256, 0, stream>>>(Hm, W2t, bcat, QS, KV);
    attn_kernel<<<25000, 256, 0, stream>>>(QS, KV, bro, ep, Wf, bfv, out);
}